// Round 1
// baseline (4857.325 us; speedup 1.0000x reference)
//
#include <hip/hip_runtime.h>
#include <math.h>

// ===================== constants =====================
static constexpr int TT  = 1024;
static constexpr int HID = 2048;
static constexpr int NH  = 16;
static constexpr int QL  = 768;
static constexpr int KVL = 512;
static constexpr int RD  = 64;     // rope dim
static constexpr int IH  = 32;     // idx heads
static constexpr int ID  = 128;    // idx dim
static constexpr int S1W = QL + KVL + RD + ID + IH;   // 1504
static constexpr int S3W = IH*ID + NH*(128+RD);       // 7168

#define SCALE_ATT 0.07216878364870323f   // 1/sqrt(192)
#define SC_IDXQ   0.08838834764831845f   // 1/sqrt(128)
#define SC_IDXW   0.17677669529663687f   // 1/sqrt(32)
#define NEGR      -1e30f
#define NEGL      -3.0e38f

// ===================== helpers =====================
__device__ __forceinline__ float blk_sum256(float v, float* s) {
  #pragma unroll
  for (int o = 32; o > 0; o >>= 1) v += __shfl_down(v, o, 64);
  __syncthreads();
  if ((threadIdx.x & 63) == 0) s[threadIdx.x >> 6] = v;
  __syncthreads();
  return s[0] + s[1] + s[2] + s[3];
}

// ===================== prelude: res = hs+resid; h = rms(res)*w =====================
__global__ __launch_bounds__(256) void k_prelude(const float* __restrict__ hs,
                                                 const float* __restrict__ rsd,
                                                 const float* __restrict__ w,
                                                 float* __restrict__ res,
                                                 float* __restrict__ h) {
  int t = blockIdx.x;
  __shared__ float scr[4];
  float vals[8]; float ss = 0.f;
  #pragma unroll
  for (int r = 0; r < 8; r++) {
    int d = threadIdx.x + 256*r;
    float v = hs[(size_t)t*HID + d] + rsd[(size_t)t*HID + d];
    vals[r] = v; res[(size_t)t*HID + d] = v; ss = fmaf(v, v, ss);
  }
  ss = blk_sum256(ss, scr);
  float inv = 1.f/sqrtf(ss/(float)HID + 1e-6f);
  #pragma unroll
  for (int r = 0; r < 8; r++) {
    int d = threadIdx.x + 256*r;
    h[(size_t)t*HID + d] = vals[r]*inv*w[d];
  }
}

// res2 = attn + res -> out; h2 = rms(res2)*w_post
__global__ __launch_bounds__(256) void k_res2(const float* __restrict__ attn,
                                              const float* __restrict__ res,
                                              const float* __restrict__ w,
                                              float* __restrict__ res2_out,
                                              float* __restrict__ h2) {
  int t = blockIdx.x;
  __shared__ float scr[4];
  float vals[8]; float ss = 0.f;
  #pragma unroll
  for (int r = 0; r < 8; r++) {
    int d = threadIdx.x + 256*r;
    float v = attn[(size_t)t*HID + d] + res[(size_t)t*HID + d];
    vals[r] = v; res2_out[(size_t)t*HID + d] = v; ss = fmaf(v, v, ss);
  }
  ss = blk_sum256(ss, scr);
  float inv = 1.f/sqrtf(ss/(float)HID + 1e-6f);
  #pragma unroll
  for (int r = 0; r < 8; r++) {
    int d = threadIdx.x + 256*r;
    h2[(size_t)t*HID + d] = vals[r]*inv*w[d];
  }
}

// ===================== rope cos/sin tables (fp64 internally) =====================
__global__ void k_ropecs(const int* __restrict__ pos, float* __restrict__ cosb, float* __restrict__ sinb) {
  int i = blockIdx.x*256 + threadIdx.x;
  if (i >= TT*32) return;
  int t = i >> 5, k = i & 31;
  double inv = pow(10000.0, -((double)(2*k))/64.0);
  double f = (double)pos[t] * inv;
  cosb[i] = (float)cos(f);
  sinb[i] = (float)sin(f);
}

// ===================== generic f32 GEMM: C(M,N) = A(M,K) * op(B) =====================
// BT=true : B is (N,K) row-major (x @ W^T).  BT=false: B is (K,N) row-major.
// M multiple of 64, K multiple of 16; N guarded.
template<bool BT, bool ACC>
__global__ __launch_bounds__(256) void k_gemm(const float* __restrict__ A, int lda, long long sA,
                                              const float* __restrict__ B, int ldb, long long sB,
                                              float* __restrict__ C, int ldc, long long sC,
                                              int M, int N, int K) {
  A += (size_t)blockIdx.z * (size_t)sA;
  B += (size_t)blockIdx.z * (size_t)sB;
  C += (size_t)blockIdx.z * (size_t)sC;
  __shared__ __align__(16) float As[16][68];
  __shared__ __align__(16) float Bs[16][68];
  int tid = threadIdx.x;
  int tx = tid & 15, ty = tid >> 4;
  int row0 = blockIdx.y * 64, col0 = blockIdx.x * 64;
  float acc[4][4] = {};
  int ar = tid >> 4, ac = tid & 15;

  for (int k0 = 0; k0 < K; k0 += 16) {
    __syncthreads();
    #pragma unroll
    for (int q = 0; q < 4; q++) {
      int m = row0 + ar + 16*q;
      As[ac][ar + 16*q] = A[(size_t)m*lda + k0 + ac];
    }
    if (BT) {
      #pragma unroll
      for (int q = 0; q < 4; q++) {
        int n = col0 + ar + 16*q;
        Bs[ac][ar + 16*q] = (n < N) ? B[(size_t)n*ldb + k0 + ac] : 0.f;
      }
    } else {
      int nl = tid & 63, kq = tid >> 6;
      #pragma unroll
      for (int q = 0; q < 4; q++) {
        int kk = kq*4 + q;
        int n = col0 + nl;
        Bs[kk][nl] = (n < N) ? B[(size_t)(k0+kk)*ldb + n] : 0.f;
      }
    }
    __syncthreads();
    #pragma unroll
    for (int kk = 0; kk < 16; kk++) {
      float4 a = *(const float4*)&As[kk][ty*4];
      float4 b = *(const float4*)&Bs[kk][tx*4];
      acc[0][0]=fmaf(a.x,b.x,acc[0][0]); acc[0][1]=fmaf(a.x,b.y,acc[0][1]);
      acc[0][2]=fmaf(a.x,b.z,acc[0][2]); acc[0][3]=fmaf(a.x,b.w,acc[0][3]);
      acc[1][0]=fmaf(a.y,b.x,acc[1][0]); acc[1][1]=fmaf(a.y,b.y,acc[1][1]);
      acc[1][2]=fmaf(a.y,b.z,acc[1][2]); acc[1][3]=fmaf(a.y,b.w,acc[1][3]);
      acc[2][0]=fmaf(a.z,b.x,acc[2][0]); acc[2][1]=fmaf(a.z,b.y,acc[2][1]);
      acc[2][2]=fmaf(a.z,b.z,acc[2][2]); acc[2][3]=fmaf(a.z,b.w,acc[2][3]);
      acc[3][0]=fmaf(a.w,b.x,acc[3][0]); acc[3][1]=fmaf(a.w,b.y,acc[3][1]);
      acc[3][2]=fmaf(a.w,b.z,acc[3][2]); acc[3][3]=fmaf(a.w,b.w,acc[3][3]);
    }
  }
  #pragma unroll
  for (int i = 0; i < 4; i++) {
    int m = row0 + ty*4 + i;
    #pragma unroll
    for (int j = 0; j < 4; j++) {
      int n = col0 + tx*4 + j;
      if (n < N) {
        size_t idx = (size_t)m*ldc + n;
        if (ACC) C[idx] = C[idx] + acc[i][j]; else C[idx] = acc[i][j];
      }
    }
  }
}

// ===================== post-s1: rms(q_c), rms(kv_c), rope(k_pe), ln+rope(idx_k), idx_w =====================
__global__ __launch_bounds__(256) void k_post1(const float* __restrict__ s1,
    const float* __restrict__ wq, const float* __restrict__ wkv,
    const float* __restrict__ lnw, const float* __restrict__ lnb,
    const float* __restrict__ cosb, const float* __restrict__ sinb,
    float* __restrict__ qc, float* __restrict__ kvc, float* __restrict__ kpe,
    float* __restrict__ idxk, float* __restrict__ idxw) {
  int t = blockIdx.x, tid = threadIdx.x;
  const float* row = s1 + (size_t)t*S1W;
  __shared__ float scr[4];
  __shared__ float yb[128];
  // q_c rms (768)
  float ss = 0.f;
  for (int d = tid; d < QL; d += 256) { float v = row[d]; ss = fmaf(v,v,ss); }
  ss = blk_sum256(ss, scr);
  float inv = 1.f/sqrtf(ss/(float)QL + 1e-6f);
  for (int d = tid; d < QL; d += 256) qc[(size_t)t*QL + d] = row[d]*inv*wq[d];
  // kv_c rms (512)
  ss = 0.f;
  for (int d = tid; d < KVL; d += 256) { float v = row[QL+d]; ss = fmaf(v,v,ss); }
  ss = blk_sum256(ss, scr);
  inv = 1.f/sqrtf(ss/(float)KVL + 1e-6f);
  for (int d = tid; d < KVL; d += 256) kvc[(size_t)t*KVL + d] = row[QL+d]*inv*wkv[d];
  // idx_k LN (128)
  float sm = (tid < 128) ? row[1344 + tid] : 0.f;
  float tot = blk_sum256(sm, scr);
  float mean = tot / 128.f;
  float vs = 0.f;
  if (tid < 128) { float v = row[1344+tid] - mean; vs = v*v; }
  vs = blk_sum256(vs, scr);
  float ivn = 1.f/sqrtf(vs/128.f + 1e-6f);
  if (tid < 128) yb[tid] = (row[1344+tid]-mean)*ivn*lnw[tid] + lnb[tid];
  __syncthreads();
  if (tid < 32) {
    float c = cosb[t*32 + tid], s = sinb[t*32 + tid];
    // idx_k rope (first 64 of 128)
    idxk[(size_t)t*ID + tid]      = yb[tid]*c - yb[32+tid]*s;
    idxk[(size_t)t*ID + 32 + tid] = yb[32+tid]*c + yb[tid]*s;
    // k_pe rope
    float x1 = row[1280+tid], x2 = row[1312+tid];
    kpe[(size_t)t*RD + tid]      = x1*c - x2*s;
    kpe[(size_t)t*RD + 32 + tid] = x2*c + x1*s;
    // idx_w
    idxw[(size_t)t*IH + tid] = row[1472+tid] * SC_IDXW;
  } else if (tid >= 64 && tid < 128) {
    idxk[(size_t)t*ID + tid] = yb[tid];
  }
}

// ===================== post-s3: rope q_pe (in place), rope+scale idx_q (in place) =====================
__global__ __launch_bounds__(256) void k_post3(float* __restrict__ s3,
                                               const float* __restrict__ cosb,
                                               const float* __restrict__ sinb) {
  int t = blockIdx.x, tid = threadIdx.x;
  float* row = s3 + (size_t)t*S3W;
  const float* cr = cosb + t*32; const float* sr = sinb + t*32;
  // idx_q rope pairs: 32 h x 32 d
  for (int p = tid; p < 1024; p += 256) {
    int h = p >> 5, d = p & 31;
    float c = cr[d], s = sr[d];
    float x1 = row[h*ID + d], x2 = row[h*ID + 32 + d];
    row[h*ID + d]      = (x1*c - x2*s) * SC_IDXQ;
    row[h*ID + 32 + d] = (x2*c + x1*s) * SC_IDXQ;
  }
  // idx_q upper half scale: 32 h x 64 d
  for (int p = tid; p < 2048; p += 256) {
    int h = p >> 6, d = 64 + (p & 63);
    row[h*ID + d] *= SC_IDXQ;
  }
  // q_pe rope: 16 h x 32 d
  for (int p = tid; p < 512; p += 256) {
    int h = p >> 5, d = p & 31;
    float c = cr[d], s = sr[d];
    int base = IH*ID + h*192 + 128;
    float x1 = row[base + d], x2 = row[base + 32 + d];
    row[base + d]      = x1*c - x2*s;
    row[base + 32 + d] = x2*c + x1*s;
  }
}

// ===================== indexer scores (rows t>=512 only) =====================
__global__ __launch_bounds__(256) void k_iscores(const float* __restrict__ s3,
                                                 const float* __restrict__ idxk,
                                                 const float* __restrict__ idxw,
                                                 float* __restrict__ isc) {
  int t = 512 + blockIdx.y;
  int s0 = blockIdx.x * 64;
  int tid = threadIdx.x;
  float* out = isc + (size_t)(t - 512) * TT;
  if (s0 > t) {
    if (tid < 64) out[s0 + tid] = NEGR;
    return;
  }
  __shared__ __align__(16) float q_lds[32*128];
  __shared__ __align__(16) float k_lds[64*128];
  __shared__ float w_lds[32];
  __shared__ float part[4][64];
  for (int e = tid; e < 4096; e += 256) q_lds[e] = s3[(size_t)t*S3W + e];
  for (int e = tid; e < 8192; e += 256) {
    int sl = e >> 7, d = e & 127;
    int p4 = (d >> 2) ^ (sl & 31);
    k_lds[sl*128 + p4*4 + (d & 3)] = idxk[(size_t)(s0 + sl)*ID + d];
  }
  if (tid < 32) w_lds[tid] = idxw[t*IH + tid];
  __syncthreads();
  int sl = tid & 63, hq = tid >> 6;
  float acc = 0.f;
  #pragma unroll 1
  for (int hh = 0; hh < 8; hh++) {
    int h = hq*8 + hh;
    const float4* qrow = (const float4*)(q_lds + h*128);
    const float4* krow = (const float4*)(k_lds + sl*128);
    float dx=0.f, dy=0.f, dz=0.f, dw=0.f;
    #pragma unroll
    for (int q4 = 0; q4 < 32; q4++) {
      float4 qa = qrow[q4];
      float4 ka = krow[q4 ^ (sl & 31)];
      dx = fmaf(qa.x, ka.x, dx); dy = fmaf(qa.y, ka.y, dy);
      dz = fmaf(qa.z, ka.z, dz); dw = fmaf(qa.w, ka.w, dw);
    }
    float dot = (dx+dy)+(dz+dw);
    acc += fmaxf(dot, 0.f) * w_lds[h];
  }
  part[hq][sl] = acc;
  __syncthreads();
  if (tid < 64) {
    int s_g = s0 + tid;
    float v = part[0][tid] + part[1][tid] + part[2][tid] + part[3][tid];
    out[s_g] = (s_g <= t) ? v : NEGR;
  }
}

// ===================== exact per-row top-512 via bitonic sort (desc, tie -> lower index) =====================
__global__ __launch_bounds__(512) void k_topk(const float* __restrict__ isc,
                                              unsigned char* __restrict__ mask) {
  int t = 512 + blockIdx.x;
  const float* row = isc + (size_t)blockIdx.x * TT;
  __shared__ unsigned long long keys[1024];
  int tid = threadIdx.x;
  for (int i = tid; i < 1024; i += 512) {
    float v = row[i];
    unsigned int b = __float_as_uint(v);
    unsigned int u = (b & 0x80000000u) ? ~b : (b | 0x80000000u);
    keys[i] = ((unsigned long long)u << 32) | (unsigned int)(1023 - i);
  }
  __syncthreads();
  for (int k = 2; k <= 1024; k <<= 1) {
    for (int j = k >> 1; j > 0; j >>= 1) {
      int i = ((tid & ~(j - 1)) << 1) | (tid & (j - 1));
      int l = i | j;
      unsigned long long a = keys[i], b = keys[l];
      bool up = ((i & k) == 0);
      if ((a < b) == up) { keys[i] = b; keys[l] = a; }  // descending
      __syncthreads();
    }
  }
  unsigned char* mrow = mask + (size_t)t * TT;
  for (int p = tid; p < 1024; p += 512) {
    int s = 1023 - (int)(keys[p] & 0xFFFFFFFFu);
    mrow[s] = (p < 512) ? (unsigned char)1 : (unsigned char)0;
  }
}

// ===================== flash attention: block = (t, 8-head group), 16-s tiles =====================
__global__ __launch_bounds__(256) void k_attn(const float* __restrict__ qln,
                                              const float* __restrict__ s3,
                                              const float* __restrict__ kvc,
                                              const float* __restrict__ kpe,
                                              const unsigned char* __restrict__ mask,
                                              float* __restrict__ obuf) {
  int t = blockIdx.x;
  int h0 = blockIdx.y * 8;
  int tid = threadIdx.x;
  __shared__ __align__(16) float q_lds[8][580];
  __shared__ __align__(16) float kv_lds[16][580];
  __shared__ float p_lds[8][16];
  __shared__ float m_sh[8], l_sh[8], sc_sh[8];
  for (int e = tid; e < 8*576; e += 256) {
    int hh = e / 576, d = e % 576;
    float v = (d < 512) ? qln[(size_t)t*(NH*512) + (h0+hh)*512 + d]
                        : s3[(size_t)t*S3W + IH*ID + (h0+hh)*192 + 128 + (d-512)];
    q_lds[hh][d] = v;
  }
  if (tid < 8) { m_sh[tid] = NEGL; l_sh[tid] = 0.f; }
  float4 o4[4];
  #pragma unroll
  for (int j = 0; j < 4; j++) o4[j] = make_float4(0.f,0.f,0.f,0.f);
  int hh = tid >> 5;                 // 0..7 head within group
  int ko = tid & 31;                 // 0..31 V-chunk
  int sl16 = tid & 15, dh = (tid >> 4) & 1;
  int ntiles = (t >> 4) + 1;
  for (int tile = 0; tile < ntiles; tile++) {
    int s0 = tile * 16;
    __syncthreads();
    for (int e = tid; e < 16*576; e += 256) {
      int sl = e / 576, d = e % 576;
      int s = s0 + sl;
      float v = (d < 512) ? kvc[(size_t)s*KVL + d] : kpe[(size_t)s*RD + (d-512)];
      kv_lds[sl][d] = v;
    }
    __syncthreads();
    { // logits
      const float4* qr = (const float4*)&q_lds[hh][0];
      const float4* kr = (const float4*)&kv_lds[sl16][0];
      int b0 = dh * 72;
      float px=0.f,py=0.f,pz=0.f,pw=0.f;
      #pragma unroll
      for (int i = 0; i < 72; i++) {
        float4 qa = qr[b0+i]; float4 ka = kr[b0+i];
        px = fmaf(qa.x,ka.x,px); py = fmaf(qa.y,ka.y,py);
        pz = fmaf(qa.z,ka.z,pz); pw = fmaf(qa.w,ka.w,pw);
      }
      float pt = (px+py)+(pz+pw);
      pt += __shfl_xor(pt, 16, 64);
      if (dh == 0) {
        int s_g = s0 + sl16;
        bool valid = (s_g <= t) && (t < 512 || mask[(size_t)t*TT + s_g] != 0);
        p_lds[hh][sl16] = valid ? pt * SCALE_ATT : NEGL;
      }
    }
    __syncthreads();
    if (tid < 8) { // online softmax update per head
      float mo = m_sh[tid];
      float tm = mo;
      #pragma unroll
      for (int s = 0; s < 16; s++) tm = fmaxf(tm, p_lds[tid][s]);
      float sc = expf(mo - tm);
      float psum = 0.f;
      #pragma unroll
      for (int s = 0; s < 16; s++) {
        float lg = p_lds[tid][s];
        float p = (lg > -1e37f) ? expf(lg - tm) : 0.f;
        p_lds[tid][s] = p; psum += p;
      }
      l_sh[tid] = l_sh[tid] * sc + psum;
      m_sh[tid] = tm;
      sc_sh[tid] = sc;
    }
    __syncthreads();
    { // PV accumulate
      float sc = sc_sh[hh];
      #pragma unroll
      for (int j = 0; j < 4; j++) { o4[j].x*=sc; o4[j].y*=sc; o4[j].z*=sc; o4[j].w*=sc; }
      #pragma unroll 1
      for (int sl = 0; sl < 16; sl++) {
        float p = p_lds[hh][sl];
        const float4* kr = (const float4*)&kv_lds[sl][0];
        #pragma unroll
        for (int j = 0; j < 4; j++) {
          float4 kv4 = kr[ko + 32*j];
          o4[j].x = fmaf(p, kv4.x, o4[j].x); o4[j].y = fmaf(p, kv4.y, o4[j].y);
          o4[j].z = fmaf(p, kv4.z, o4[j].z); o4[j].w = fmaf(p, kv4.w, o4[j].w);
        }
      }
    }
  }
  float invl = 1.f / l_sh[hh];
  float4* orow = (float4*)(obuf + (size_t)t*(NH*512) + (h0+hh)*512);
  #pragma unroll
  for (int j = 0; j < 4; j++) {
    float4 r = o4[j];
    r.x*=invl; r.y*=invl; r.z*=invl; r.w*=invl;
    orow[ko + 32*j] = r;
  }
}

// ===================== gating / routing =====================
__global__ __launch_bounds__(256) void k_gate(const float* __restrict__ h2,
                                              const float* __restrict__ gw,
                                              const float* __restrict__ gb,
                                              float* __restrict__ comb) {
  int t = blockIdx.x, tid = threadIdx.x;
  int e = tid >> 5, lane = tid & 31;
  __shared__ float gl[8];
  float p = 0.f;
  for (int d = lane; d < HID; d += 32) p = fmaf(h2[(size_t)t*HID+d], gw[(size_t)e*HID+d], p);
  #pragma unroll
  for (int o = 16; o > 0; o >>= 1) p += __shfl_down(p, o, 32);
  if (lane == 0) gl[e] = p;
  __syncthreads();
  if (tid == 0) {
    float sg[8], sc[8];
    #pragma unroll
    for (int i = 0; i < 8; i++) { sg[i] = 1.f/(1.f+expf(-gl[i])); sc[i] = sg[i] + gb[i]; }
    float gs[4];
    #pragma unroll
    for (int g = 0; g < 4; g++) gs[g] = sc[2*g] + sc[2*g+1];
    int g0 = 0;
    for (int g = 1; g < 4; g++) if (gs[g] > gs[g0]) g0 = g;
    int g1 = -1;
    for (int g = 0; g < 4; g++) { if (g == g0) continue; if (g1 < 0 || gs[g] > gs[g1]) g1 = g; }
    float wsum = 1e-20f;
    #pragma unroll
    for (int i = 0; i < 8; i++) { int g = i >> 1; if (g == g0 || g == g1) wsum += sg[i]; }
    #pragma unroll
    for (int i = 0; i < 8; i++) { int g = i >> 1; comb[t*8+i] = (g == g0 || g == g1) ? sg[i]/wsum*2.5f : 0.f; }
  }
}

// ===================== swiglu (optionally scaled by comb[t,e]) =====================
__global__ __launch_bounds__(256) void k_swiglu(const float* __restrict__ gus,
                                                const float* __restrict__ comb, int e,
                                                float* __restrict__ act) {
  int i = blockIdx.x*256 + threadIdx.x;   // < TT*512
  int t = i >> 9, c = i & 511;
  float g = gus[(size_t)t*1024 + c], u = gus[(size_t)t*1024 + 512 + c];
  float sv = g / (1.f + expf(-g));
  float w = comb ? comb[t*8 + e] : 1.f;
  act[(size_t)t*512 + c] = sv * u * w;
}

__global__ void k_add(const float* __restrict__ a, const float* __restrict__ b, float* __restrict__ o) {
  int i = blockIdx.x*256 + threadIdx.x;
  o[i] = a[i] + b[i];
}

// ===================== launch =====================
extern "C" void kernel_launch(void* const* d_in, const int* in_sizes, int n_in,
                              void* d_out, int out_size, void* d_ws, size_t ws_size,
                              hipStream_t stream) {
  const int*   positions = (const int*)d_in[0];
  const float* hs     = (const float*)d_in[1];
  const float* rsd    = (const float*)d_in[2];
  const float* w_in   = (const float*)d_in[3];
  const float* w_post = (const float*)d_in[4];
  const float* w_s1   = (const float*)d_in[5];
  const float* w_qln  = (const float*)d_in[6];
  const float* w_kvln = (const float*)d_in[7];
  const float* iklnw  = (const float*)d_in[8];
  const float* iklnb  = (const float*)d_in[9];
  const float* w_s3   = (const float*)d_in[10];
  const float* wukt   = (const float*)d_in[11];
  const float* wuv    = (const float*)d_in[12];
  const float* w_o    = (const float*)d_in[13];
  const float* gate_w = (const float*)d_in[14];
  const float* gate_b = (const float*)d_in[15];
  const float* sh_gu  = (const float*)d_in[16];
  const float* sh_dn  = (const float*)d_in[17];
  const float* ex_gu  = (const float*)d_in[18];
  const float* ex_dn  = (const float*)d_in[19];

  float* ws = (float*)d_ws;
  // -------- workspace layout (floats), with aliasing --------
  float* RES   = ws + 0;                         // 2,097,152
  float* H     = ws + 2097152;                   // 2,097,152  (later h2)
  float* S1    = ws + 4194304;                   // 1,540,096  (later attn_out region start)
  float* QC    = ws + 5734400;                   //   786,432
  float* KVC   = ws + 6520832;                   //   524,288
  float* KPE   = ws + 7045120;                   //    65,536
  float* IDXK  = ws + 7110656;                   //   131,072
  float* IDXW  = ws + 7241728;                   //    32,768
  float* COSB  = ws + 7274496;                   //    32,768
  float* SINB  = ws + 7307264;                   //    32,768
  float* S3    = ws + 7340032;                   // 7,340,032
  float* QLN   = ws + 14680064;                  // 8,388,608
  float* ISC   = ws + 23068672;                  //   524,288 (rows 512..1023)
  unsigned char* MASK = (unsigned char*)(ws + 23592960); // 1,048,576 bytes
  float* BIGB  = ws + 23855104;                  // 8,388,608 : OBUF; later SHARED/GUS/ACTE
  float* O2R   = ws + 32243712;                  // 2,097,152 : o2, later routed
  float* COMB  = ws + 34340864;                  //     8,192
  // end = 34,349,056 floats = 137.4 MB

  float* OBUF   = BIGB;
  float* SHARED = BIGB;
  float* GUS    = BIGB + 2097152;
  float* ACTE   = BIGB + 3145728;
  float* ATTN   = S1;          // alias: s1/qc dead by then
  float* H2     = H;           // alias: h dead after s1 GEMM
  float* ROUTED = O2R;         // alias: o2 dead after w_o GEMM

  float* OUT0 = (float*)d_out;
  float* OUT_RES2 = OUT0 + (size_t)TT*HID;

  // 1. res = hs + residual ; h = rms(res)*w_in
  k_prelude<<<TT, 256, 0, stream>>>(hs, rsd, w_in, RES, H);
  // 2. cos/sin tables
  k_ropecs<<<(TT*32)/256, 256, 0, stream>>>(positions, COSB, SINB);
  // 3. s1 = h @ w_step1^T   (1024 x 1504, K=2048)
  k_gemm<true,false><<<dim3(24,16,1), 256, 0, stream>>>(H, HID, 0, w_s1, HID, 0, S1, S1W, 0, TT, S1W, HID);
  // 4. post-s1
  k_post1<<<TT, 256, 0, stream>>>(S1, w_qln, w_kvln, iklnw, iklnb, COSB, SINB, QC, KVC, KPE, IDXK, IDXW);
  // 5. s3 = q_c @ w_step3^T (1024 x 7168, K=768)
  k_gemm<true,false><<<dim3(112,16,1), 256, 0, stream>>>(QC, QL, 0, w_s3, QL, 0, S3, S3W, 0, TT, S3W, QL);
  // 6. post-s3 (rope q_pe, rope+scale idx_q in place)
  k_post3<<<TT, 256, 0, stream>>>(S3, COSB, SINB);
  // 7. ql_nope = einsum(q_nope, W_UK_T) : batched (16) GEMM, B is (K=128,N=512)
  k_gemm<false,false><<<dim3(8,16,16), 256, 0, stream>>>(S3 + IH*ID, S3W, 192, wukt, 512, 65536, QLN, NH*512, 512, TT, 512, 128);
  // 8. indexer scores (rows t>=512)
  k_iscores<<<dim3(16,512), 256, 0, stream>>>(S3, IDXK, IDXW, ISC);
  // 9. exact top-512 mask
  k_topk<<<512, 512, 0, stream>>>(ISC, MASK);
  // 10. flash attention
  k_attn<<<dim3(TT,2), 256, 0, stream>>>(QLN, S3, KVC, KPE, MASK, OBUF);
  // 11. o2 = o @ W_UV : batched (16), B is (K=512,N=128)
  k_gemm<false,false><<<dim3(2,16,16), 256, 0, stream>>>(OBUF, NH*512, 512, wuv, 128, 65536, O2R, HID, 128, TT, 128, 512);
  // 12. attn_out = o2 @ w_o^T
  k_gemm<true,false><<<dim3(32,16,1), 256, 0, stream>>>(O2R, HID, 0, w_o, HID, 0, ATTN, HID, 0, TT, HID, HID);
  // 13. res2 (-> d_out second half) + h2
  k_res2<<<TT, 256, 0, stream>>>(ATTN, RES, w_post, OUT_RES2, H2);
  // 14. routing
  k_gate<<<TT, 256, 0, stream>>>(H2, gate_w, gate_b, COMB);
  // 15-17. shared expert
  k_gemm<true,false><<<dim3(16,16,1), 256, 0, stream>>>(H2, HID, 0, sh_gu, HID, 0, GUS, 1024, 0, TT, 1024, HID);
  k_swiglu<<<(TT*512)/256, 256, 0, stream>>>(GUS, nullptr, 0, ACTE);
  k_gemm<true,false><<<dim3(32,16,1), 256, 0, stream>>>(ACTE, 512, 0, sh_dn, 512, 0, SHARED, HID, 0, TT, HID, 512);
  // 18. routed experts (dense; comb folded into act, so unselected contribute exactly 0)
  for (int e = 0; e < 8; e++) {
    k_gemm<true,false><<<dim3(16,16,1), 256, 0, stream>>>(H2, HID, 0, ex_gu + (size_t)e*1024*HID, HID, 0, GUS, 1024, 0, TT, 1024, HID);
    k_swiglu<<<(TT*512)/256, 256, 0, stream>>>(GUS, COMB, e, ACTE);
    if (e == 0)
      k_gemm<true,false><<<dim3(32,16,1), 256, 0, stream>>>(ACTE, 512, 0, ex_dn + (size_t)e*HID*512, 512, 0, ROUTED, HID, 0, TT, HID, 512);
    else
      k_gemm<true,true><<<dim3(32,16,1), 256, 0, stream>>>(ACTE, 512, 0, ex_dn + (size_t)e*HID*512, 512, 0, ROUTED, HID, 0, TT, HID, 512);
  }
  // 19. out = shared + routed
  k_add<<<(TT*HID)/256, 256, 0, stream>>>(SHARED, ROUTED, OUT0);
}

// Round 2
// 1735.659 us; speedup vs baseline: 2.7985x; 2.7985x over previous
//
#include <hip/hip_runtime.h>
#include <math.h>

// ===================== constants =====================
static constexpr int TT  = 1024;
static constexpr int HID = 2048;
static constexpr int NH  = 16;
static constexpr int QL  = 768;
static constexpr int KVL = 512;
static constexpr int RD  = 64;     // rope dim
static constexpr int IH  = 32;     // idx heads
static constexpr int ID  = 128;    // idx dim
static constexpr int S1W = QL + KVL + RD + ID + IH;   // 1504
static constexpr int S3W = IH*ID + NH*(128+RD);       // 7168

#define SCALE_ATT 0.07216878364870323f   // 1/sqrt(192)
#define SC_IDXQ   0.08838834764831845f   // 1/sqrt(128)
#define SC_IDXW   0.17677669529663687f   // 1/sqrt(32)
#define NEGR      -1e30f
#define NEGL      -3.0e38f

typedef __bf16 bf16x8 __attribute__((ext_vector_type(8)));
typedef float  f32x4  __attribute__((ext_vector_type(4)));

// bf16 <-> f32 helpers (RNE)
__device__ __forceinline__ unsigned short f2b(float x) {
  union { float f; unsigned u; } v; v.f = x;
  unsigned r = v.u + 0x7FFFu + ((v.u >> 16) & 1u);
  return (unsigned short)(r >> 16);
}
__device__ __forceinline__ float b2f(unsigned short u) {
  union { unsigned u; float f; } v; v.u = ((unsigned)u) << 16;
  return v.f;
}

// ===================== helpers =====================
__device__ __forceinline__ float blk_sum256(float v, float* s) {
  #pragma unroll
  for (int o = 32; o > 0; o >>= 1) v += __shfl_down(v, o, 64);
  __syncthreads();
  if ((threadIdx.x & 63) == 0) s[threadIdx.x >> 6] = v;
  __syncthreads();
  return s[0] + s[1] + s[2] + s[3];
}

// ===================== prelude: res = hs+resid; hb = bf16(rms(res)*w) =====================
__global__ __launch_bounds__(256) void k_prelude(const float* __restrict__ hs,
                                                 const float* __restrict__ rsd,
                                                 const float* __restrict__ w,
                                                 float* __restrict__ res,
                                                 unsigned short* __restrict__ hb) {
  int t = blockIdx.x;
  __shared__ float scr[4];
  float vals[8]; float ss = 0.f;
  #pragma unroll
  for (int r = 0; r < 8; r++) {
    int d = threadIdx.x + 256*r;
    float v = hs[(size_t)t*HID + d] + rsd[(size_t)t*HID + d];
    vals[r] = v; res[(size_t)t*HID + d] = v; ss = fmaf(v, v, ss);
  }
  ss = blk_sum256(ss, scr);
  float inv = 1.f/sqrtf(ss/(float)HID + 1e-6f);
  #pragma unroll
  for (int r = 0; r < 8; r++) {
    int d = threadIdx.x + 256*r;
    hb[(size_t)t*HID + d] = f2b(vals[r]*inv*w[d]);
  }
}

// res2 = attn + res -> d_out; h2 f32 + h2 bf16
__global__ __launch_bounds__(256) void k_res2(const float* __restrict__ attn,
                                              const float* __restrict__ res,
                                              const float* __restrict__ w,
                                              float* __restrict__ res2_out,
                                              float* __restrict__ h2,
                                              unsigned short* __restrict__ h2b) {
  int t = blockIdx.x;
  __shared__ float scr[4];
  float vals[8]; float ss = 0.f;
  #pragma unroll
  for (int r = 0; r < 8; r++) {
    int d = threadIdx.x + 256*r;
    float v = attn[(size_t)t*HID + d] + res[(size_t)t*HID + d];
    vals[r] = v; res2_out[(size_t)t*HID + d] = v; ss = fmaf(v, v, ss);
  }
  ss = blk_sum256(ss, scr);
  float inv = 1.f/sqrtf(ss/(float)HID + 1e-6f);
  #pragma unroll
  for (int r = 0; r < 8; r++) {
    int d = threadIdx.x + 256*r;
    float o = vals[r]*inv*w[d];
    h2[(size_t)t*HID + d] = o;
    h2b[(size_t)t*HID + d] = f2b(o);
  }
}

// ===================== rope cos/sin tables (fp64 internally) =====================
__global__ void k_ropecs(const int* __restrict__ pos, float* __restrict__ cosb, float* __restrict__ sinb) {
  int i = blockIdx.x*256 + threadIdx.x;
  if (i >= TT*32) return;
  int t = i >> 5, k = i & 31;
  double inv = pow(10000.0, -((double)(2*k))/64.0);
  double f = (double)pos[t] * inv;
  cosb[i] = (float)cos(f);
  sinb[i] = (float)sin(f);
}

// ===================== f32 -> bf16 convert (with zero tail pad) =====================
__global__ void k_f2b(const float* __restrict__ s, unsigned short* __restrict__ d,
                      long long n, long long ntot) {
  long long stride = (long long)gridDim.x * 1024;
  for (long long i = ((long long)blockIdx.x*256 + threadIdx.x)*4; i < ntot; i += stride) {
    float x0, x1, x2, x3;
    if (i + 3 < n) { float4 v = *(const float4*)(s + i); x0=v.x; x1=v.y; x2=v.z; x3=v.w; }
    else {
      x0 = (i   < n) ? s[i]   : 0.f; x1 = (i+1 < n) ? s[i+1] : 0.f;
      x2 = (i+2 < n) ? s[i+2] : 0.f; x3 = (i+3 < n) ? s[i+3] : 0.f;
    }
    ushort4 o; o.x=f2b(x0); o.y=f2b(x1); o.z=f2b(x2); o.w=f2b(x3);
    *(ushort4*)(d + i) = o;
  }
}

// ===================== transpose + convert: src (R,C) f32 -> dst (C,R) bf16, batched z =====================
__global__ __launch_bounds__(256) void k_tconvb(const float* __restrict__ src,
                                                unsigned short* __restrict__ dst,
                                                int R, int C) {
  src += (size_t)blockIdx.z * R * C;
  dst += (size_t)blockIdx.z * R * C;
  __shared__ float tile[32][33];
  int c0 = blockIdx.x * 32, r0 = blockIdx.y * 32;
  int tx = threadIdx.x & 31, ty = threadIdx.x >> 5;
  #pragma unroll
  for (int i = 0; i < 4; i++) {
    int r = r0 + ty + i*8;
    tile[ty + i*8][tx] = src[(size_t)r*C + c0 + tx];
  }
  __syncthreads();
  #pragma unroll
  for (int i = 0; i < 4; i++) {
    int c = c0 + ty + i*8;
    dst[(size_t)c*R + r0 + tx] = f2b(tile[tx][ty + i*8]);
  }
}

// ===================== MFMA bf16 GEMM: C(M,N) = A(M,K) @ B(N,K)^T =====================
// A,B bf16 (ushort). 128x128 tile, 4 waves (2x2), BK=64, XOR-swizzled LDS.
// M assumed multiple of 128 (rows fully valid); B rows padded to N tiles; C write guarded n<N.
// nseg>1: accumulate over segments (A += segA, B += segB per segment) — used for MoE down.
template<bool STORE_BF16>
__global__ __launch_bounds__(256) void k_mgemm(const unsigned short* __restrict__ A, int lda, long long sA,
                                               const unsigned short* __restrict__ B, int ldb, long long sB,
                                               void* __restrict__ Cv, int ldc, long long sC,
                                               int N, int K, int nseg, long long segA, long long segB) {
  __shared__ __align__(16) unsigned short As[128*64];
  __shared__ __align__(16) unsigned short Bs[128*64];
  const int tid  = threadIdx.x;
  const int wave = tid >> 6, lane = tid & 63;
  const int wm = wave >> 1, wn = wave & 1;
  const int row0 = blockIdx.y * 128;
  const int col0 = blockIdx.x * 128;
  A += (size_t)blockIdx.z * (size_t)sA;
  B += (size_t)blockIdx.z * (size_t)sB;

  f32x4 acc[4][4] = {};

  const int l15 = lane & 15, l4 = lane >> 4;
  const int sx = l15 & 7;

  for (int seg = 0; seg < nseg; seg++) {
    const unsigned short* Ab = A + (size_t)seg * segA;
    const unsigned short* Bb = B + (size_t)seg * segB;
    for (int k0 = 0; k0 < K; k0 += 64) {
      __syncthreads();
      #pragma unroll
      for (int it = 0; it < 4; it++) {
        int sidx = tid + 256*it;          // 0..1023 (128 rows x 8 slots)
        int r = sidx >> 3, s = sidx & 7;
        int ldsoff = r*64 + ((s ^ (r & 7)) << 3);
        uint4 va = *(const uint4*)(Ab + (size_t)(row0 + r)*lda + k0 + s*8);
        *(uint4*)&As[ldsoff] = va;
        uint4 vb = *(const uint4*)(Bb + (size_t)(col0 + r)*ldb + k0 + s*8);
        *(uint4*)&Bs[ldsoff] = vb;
      }
      __syncthreads();
      #pragma unroll
      for (int kc = 0; kc < 2; kc++) {
        const int sl = ((kc*4 + l4) ^ sx) << 3;
        bf16x8 fa[4], fb[4];
        #pragma unroll
        for (int mf = 0; mf < 4; mf++)
          fa[mf] = *(const bf16x8*)&As[(wm*64 + mf*16 + l15)*64 + sl];
        #pragma unroll
        for (int nf = 0; nf < 4; nf++)
          fb[nf] = *(const bf16x8*)&Bs[(wn*64 + nf*16 + l15)*64 + sl];
        #pragma unroll
        for (int mf = 0; mf < 4; mf++)
          #pragma unroll
          for (int nf = 0; nf < 4; nf++)
            acc[mf][nf] = __builtin_amdgcn_mfma_f32_16x16x32_bf16(fa[mf], fb[nf], acc[mf][nf], 0, 0, 0);
      }
    }
  }

  // C write: col = lane&15, row = (lane>>4)*4 + reg  [m89-verified]
  #pragma unroll
  for (int mf = 0; mf < 4; mf++) {
    #pragma unroll
    for (int nf = 0; nf < 4; nf++) {
      int n = col0 + wn*64 + nf*16 + l15;
      if (n < N) {
        #pragma unroll
        for (int r = 0; r < 4; r++) {
          int m = row0 + wm*64 + mf*16 + l4*4 + r;
          size_t idx = (size_t)m*ldc + n;
          float v = acc[mf][nf][r];
          if (STORE_BF16) ((unsigned short*)Cv)[(size_t)blockIdx.z*sC + idx] = f2b(v);
          else            ((float*)Cv)[(size_t)blockIdx.z*sC + idx] = v;
        }
      }
    }
  }
}

// ===================== post-s1 =====================
__global__ __launch_bounds__(256) void k_post1(const float* __restrict__ s1,
    const float* __restrict__ wq, const float* __restrict__ wkv,
    const float* __restrict__ lnw, const float* __restrict__ lnb,
    const float* __restrict__ cosb, const float* __restrict__ sinb,
    unsigned short* __restrict__ qcb, float* __restrict__ kvc, float* __restrict__ kpe,
    float* __restrict__ idxk, float* __restrict__ idxw) {
  int t = blockIdx.x, tid = threadIdx.x;
  const float* row = s1 + (size_t)t*S1W;
  __shared__ float scr[4];
  __shared__ float yb[128];
  float ss = 0.f;
  for (int d = tid; d < QL; d += 256) { float v = row[d]; ss = fmaf(v,v,ss); }
  ss = blk_sum256(ss, scr);
  float inv = 1.f/sqrtf(ss/(float)QL + 1e-6f);
  for (int d = tid; d < QL; d += 256) qcb[(size_t)t*QL + d] = f2b(row[d]*inv*wq[d]);
  ss = 0.f;
  for (int d = tid; d < KVL; d += 256) { float v = row[QL+d]; ss = fmaf(v,v,ss); }
  ss = blk_sum256(ss, scr);
  inv = 1.f/sqrtf(ss/(float)KVL + 1e-6f);
  for (int d = tid; d < KVL; d += 256) kvc[(size_t)t*KVL + d] = row[QL+d]*inv*wkv[d];
  float sm = (tid < 128) ? row[1344 + tid] : 0.f;
  float tot = blk_sum256(sm, scr);
  float mean = tot / 128.f;
  float vs = 0.f;
  if (tid < 128) { float v = row[1344+tid] - mean; vs = v*v; }
  vs = blk_sum256(vs, scr);
  float ivn = 1.f/sqrtf(vs/128.f + 1e-6f);
  if (tid < 128) yb[tid] = (row[1344+tid]-mean)*ivn*lnw[tid] + lnb[tid];
  __syncthreads();
  if (tid < 32) {
    float c = cosb[t*32 + tid], s = sinb[t*32 + tid];
    idxk[(size_t)t*ID + tid]      = yb[tid]*c - yb[32+tid]*s;
    idxk[(size_t)t*ID + 32 + tid] = yb[32+tid]*c + yb[tid]*s;
    float x1 = row[1280+tid], x2 = row[1312+tid];
    kpe[(size_t)t*RD + tid]      = x1*c - x2*s;
    kpe[(size_t)t*RD + 32 + tid] = x2*c + x1*s;
    idxw[(size_t)t*IH + tid] = row[1472+tid] * SC_IDXW;
  } else if (tid >= 64 && tid < 128) {
    idxk[(size_t)t*ID + tid] = yb[tid];
  }
}

// ===================== post-s3 (in place f32) =====================
__global__ __launch_bounds__(256) void k_post3(float* __restrict__ s3,
                                               const float* __restrict__ cosb,
                                               const float* __restrict__ sinb) {
  int t = blockIdx.x, tid = threadIdx.x;
  float* row = s3 + (size_t)t*S3W;
  const float* cr = cosb + t*32; const float* sr = sinb + t*32;
  for (int p = tid; p < 1024; p += 256) {
    int h = p >> 5, d = p & 31;
    float c = cr[d], s = sr[d];
    float x1 = row[h*ID + d], x2 = row[h*ID + 32 + d];
    row[h*ID + d]      = (x1*c - x2*s) * SC_IDXQ;
    row[h*ID + 32 + d] = (x2*c + x1*s) * SC_IDXQ;
  }
  for (int p = tid; p < 2048; p += 256) {
    int h = p >> 6, d = 64 + (p & 63);
    row[h*ID + d] *= SC_IDXQ;
  }
  for (int p = tid; p < 512; p += 256) {
    int h = p >> 5, d = p & 31;
    float c = cr[d], s = sr[d];
    int base = IH*ID + h*192 + 128;
    float x1 = row[base + d], x2 = row[base + 32 + d];
    row[base + d]      = x1*c - x2*s;
    row[base + 32 + d] = x2*c + x1*s;
  }
}

// ===================== indexer scores (rows t>=512 only) =====================
__global__ __launch_bounds__(256) void k_iscores(const unsigned short* __restrict__ s3b,
                                                 const float* __restrict__ idxk,
                                                 const float* __restrict__ idxw,
                                                 float* __restrict__ isc) {
  int t = 512 + blockIdx.y;
  int s0 = blockIdx.x * 64;
  int tid = threadIdx.x;
  float* out = isc + (size_t)(t - 512) * TT;
  if (s0 > t) {
    if (tid < 64) out[s0 + tid] = NEGR;
    return;
  }
  __shared__ __align__(16) float q_lds[32*128];
  __shared__ __align__(16) float k_lds[64*128];
  __shared__ float w_lds[32];
  __shared__ float part[4][64];
  for (int e = tid; e < 4096; e += 256) q_lds[e] = b2f(s3b[(size_t)t*S3W + e]);
  for (int e = tid; e < 8192; e += 256) {
    int sl = e >> 7, d = e & 127;
    int p4 = (d >> 2) ^ (sl & 31);
    k_lds[sl*128 + p4*4 + (d & 3)] = idxk[(size_t)(s0 + sl)*ID + d];
  }
  if (tid < 32) w_lds[tid] = idxw[t*IH + tid];
  __syncthreads();
  int sl = tid & 63, hq = tid >> 6;
  float acc = 0.f;
  #pragma unroll 1
  for (int hh = 0; hh < 8; hh++) {
    int h = hq*8 + hh;
    const float4* qrow = (const float4*)(q_lds + h*128);
    const float4* krow = (const float4*)(k_lds + sl*128);
    float dx=0.f, dy=0.f, dz=0.f, dw=0.f;
    #pragma unroll
    for (int q4 = 0; q4 < 32; q4++) {
      float4 qa = qrow[q4];
      float4 ka = krow[q4 ^ (sl & 31)];
      dx = fmaf(qa.x, ka.x, dx); dy = fmaf(qa.y, ka.y, dy);
      dz = fmaf(qa.z, ka.z, dz); dw = fmaf(qa.w, ka.w, dw);
    }
    float dot = (dx+dy)+(dz+dw);
    acc += fmaxf(dot, 0.f) * w_lds[h];
  }
  part[hq][sl] = acc;
  __syncthreads();
  if (tid < 64) {
    int s_g = s0 + tid;
    float v = part[0][tid] + part[1][tid] + part[2][tid] + part[3][tid];
    out[s_g] = (s_g <= t) ? v : NEGR;
  }
}

// ===================== exact per-row top-512 (bitonic, tie -> lower index) =====================
__global__ __launch_bounds__(512) void k_topk(const float* __restrict__ isc,
                                              unsigned char* __restrict__ mask) {
  int t = 512 + blockIdx.x;
  const float* row = isc + (size_t)blockIdx.x * TT;
  __shared__ unsigned long long keys[1024];
  int tid = threadIdx.x;
  for (int i = tid; i < 1024; i += 512) {
    float v = row[i];
    unsigned int b = __float_as_uint(v);
    unsigned int u = (b & 0x80000000u) ? ~b : (b | 0x80000000u);
    keys[i] = ((unsigned long long)u << 32) | (unsigned int)(1023 - i);
  }
  __syncthreads();
  for (int k = 2; k <= 1024; k <<= 1) {
    for (int j = k >> 1; j > 0; j >>= 1) {
      int i = ((tid & ~(j - 1)) << 1) | (tid & (j - 1));
      int l = i | j;
      unsigned long long a = keys[i], b = keys[l];
      bool up = ((i & k) == 0);
      if ((a < b) == up) { keys[i] = b; keys[l] = a; }
      __syncthreads();
    }
  }
  unsigned char* mrow = mask + (size_t)t * TT;
  for (int p = tid; p < 1024; p += 512) {
    int s = 1023 - (int)(keys[p] & 0xFFFFFFFFu);
    mrow[s] = (p < 512) ? (unsigned char)1 : (unsigned char)0;
  }
}

// ===================== flash attention =====================
__global__ __launch_bounds__(256) void k_attn(const unsigned short* __restrict__ qlnb,
                                              const unsigned short* __restrict__ s3b,
                                              const float* __restrict__ kvc,
                                              const float* __restrict__ kpe,
                                              const unsigned char* __restrict__ mask,
                                              unsigned short* __restrict__ obufb) {
  int t = blockIdx.x;
  int h0 = blockIdx.y * 8;
  int tid = threadIdx.x;
  __shared__ __align__(16) float q_lds[8][580];
  __shared__ __align__(16) float kv_lds[16][580];
  __shared__ float p_lds[8][16];
  __shared__ float m_sh[8], l_sh[8], sc_sh[8];
  for (int e = tid; e < 8*576; e += 256) {
    int hh = e / 576, d = e % 576;
    float v = (d < 512) ? b2f(qlnb[(size_t)t*(NH*512) + (h0+hh)*512 + d])
                        : b2f(s3b[(size_t)t*S3W + IH*ID + (h0+hh)*192 + 128 + (d-512)]);
    q_lds[hh][d] = v;
  }
  if (tid < 8) { m_sh[tid] = NEGL; l_sh[tid] = 0.f; }
  float4 o4[4];
  #pragma unroll
  for (int j = 0; j < 4; j++) o4[j] = make_float4(0.f,0.f,0.f,0.f);
  int hh = tid >> 5;
  int ko = tid & 31;
  int sl16 = tid & 15, dh = (tid >> 4) & 1;
  int ntiles = (t >> 4) + 1;
  for (int tile = 0; tile < ntiles; tile++) {
    int s0 = tile * 16;
    __syncthreads();
    for (int e = tid; e < 16*576; e += 256) {
      int sl = e / 576, d = e % 576;
      int s = s0 + sl;
      float v = (d < 512) ? kvc[(size_t)s*KVL + d] : kpe[(size_t)s*RD + (d-512)];
      kv_lds[sl][d] = v;
    }
    __syncthreads();
    {
      const float4* qr = (const float4*)&q_lds[hh][0];
      const float4* kr = (const float4*)&kv_lds[sl16][0];
      int b0 = dh * 72;
      float px=0.f,py=0.f,pz=0.f,pw=0.f;
      #pragma unroll
      for (int i = 0; i < 72; i++) {
        float4 qa = qr[b0+i]; float4 ka = kr[b0+i];
        px = fmaf(qa.x,ka.x,px); py = fmaf(qa.y,ka.y,py);
        pz = fmaf(qa.z,ka.z,pz); pw = fmaf(qa.w,ka.w,pw);
      }
      float pt = (px+py)+(pz+pw);
      pt += __shfl_xor(pt, 16, 64);
      if (dh == 0) {
        int s_g = s0 + sl16;
        bool valid = (s_g <= t) && (t < 512 || mask[(size_t)t*TT + s_g] != 0);
        p_lds[hh][sl16] = valid ? pt * SCALE_ATT : NEGL;
      }
    }
    __syncthreads();
    if (tid < 8) {
      float mo = m_sh[tid];
      float tm = mo;
      #pragma unroll
      for (int s = 0; s < 16; s++) tm = fmaxf(tm, p_lds[tid][s]);
      float sc = expf(mo - tm);
      float psum = 0.f;
      #pragma unroll
      for (int s = 0; s < 16; s++) {
        float lg = p_lds[tid][s];
        float p = (lg > -1e37f) ? expf(lg - tm) : 0.f;
        p_lds[tid][s] = p; psum += p;
      }
      l_sh[tid] = l_sh[tid] * sc + psum;
      m_sh[tid] = tm;
      sc_sh[tid] = sc;
    }
    __syncthreads();
    {
      float sc = sc_sh[hh];
      #pragma unroll
      for (int j = 0; j < 4; j++) { o4[j].x*=sc; o4[j].y*=sc; o4[j].z*=sc; o4[j].w*=sc; }
      #pragma unroll 1
      for (int sl = 0; sl < 16; sl++) {
        float p = p_lds[hh][sl];
        const float4* kr = (const float4*)&kv_lds[sl][0];
        #pragma unroll
        for (int j = 0; j < 4; j++) {
          float4 kv4 = kr[ko + 32*j];
          o4[j].x = fmaf(p, kv4.x, o4[j].x); o4[j].y = fmaf(p, kv4.y, o4[j].y);
          o4[j].z = fmaf(p, kv4.z, o4[j].z); o4[j].w = fmaf(p, kv4.w, o4[j].w);
        }
      }
    }
  }
  float invl = 1.f / l_sh[hh];
  unsigned short* orow = obufb + (size_t)t*(NH*512) + (h0+hh)*512;
  #pragma unroll
  for (int j = 0; j < 4; j++) {
    int base = (ko + 32*j)*4;
    orow[base+0] = f2b(o4[j].x*invl);
    orow[base+1] = f2b(o4[j].y*invl);
    orow[base+2] = f2b(o4[j].z*invl);
    orow[base+3] = f2b(o4[j].w*invl);
  }
}

// ===================== gating / routing (f32 exact) =====================
__global__ __launch_bounds__(256) void k_gate(const float* __restrict__ h2,
                                              const float* __restrict__ gw,
                                              const float* __restrict__ gb,
                                              float* __restrict__ comb) {
  int t = blockIdx.x, tid = threadIdx.x;
  int e = tid >> 5, lane = tid & 31;
  __shared__ float gl[8];
  float p = 0.f;
  for (int d = lane; d < HID; d += 32) p = fmaf(h2[(size_t)t*HID+d], gw[(size_t)e*HID+d], p);
  #pragma unroll
  for (int o = 16; o > 0; o >>= 1) p += __shfl_down(p, o, 32);
  if (lane == 0) gl[e] = p;
  __syncthreads();
  if (tid == 0) {
    float sg[8], sc[8];
    #pragma unroll
    for (int i = 0; i < 8; i++) { sg[i] = 1.f/(1.f+expf(-gl[i])); sc[i] = sg[i] + gb[i]; }
    float gs[4];
    #pragma unroll
    for (int g = 0; g < 4; g++) gs[g] = sc[2*g] + sc[2*g+1];
    int g0 = 0;
    for (int g = 1; g < 4; g++) if (gs[g] > gs[g0]) g0 = g;
    int g1 = -1;
    for (int g = 0; g < 4; g++) { if (g == g0) continue; if (g1 < 0 || gs[g] > gs[g1]) g1 = g; }
    float wsum = 1e-20f;
    #pragma unroll
    for (int i = 0; i < 8; i++) { int g = i >> 1; if (g == g0 || g == g1) wsum += sg[i]; }
    #pragma unroll
    for (int i = 0; i < 8; i++) { int g = i >> 1; comb[t*8+i] = (g == g0 || g == g1) ? sg[i]/wsum*2.5f : 0.f; }
  }
}

// ===================== swiglu variants =====================
__global__ void k_swiglu_sh(const float* __restrict__ gus, unsigned short* __restrict__ act) {
  int i = blockIdx.x*256 + threadIdx.x;   // < 1024*512
  int t = i >> 9, c = i & 511;
  float g = gus[(size_t)t*1024 + c], u = gus[(size_t)t*1024 + 512 + c];
  act[i] = f2b(g/(1.f + expf(-g)) * u);
}
__global__ void k_swiglu8(const float* __restrict__ gus8, const float* __restrict__ comb,
                          unsigned short* __restrict__ act8) {
  long long i = (long long)blockIdx.x*256 + threadIdx.x;  // < 8*1024*512
  int e = (int)(i >> 19);
  int rem = (int)(i & 524287);
  int t = rem >> 9, c = rem & 511;
  const float* g0 = gus8 + (size_t)e*1048576 + (size_t)t*1024;
  float g = g0[c], u = g0[512 + c];
  act8[i] = f2b(g/(1.f + expf(-g)) * u * comb[t*8 + e]);
}

__global__ void k_add(const float* __restrict__ a, const float* __restrict__ b, float* __restrict__ o) {
  int i = blockIdx.x*256 + threadIdx.x;
  o[i] = a[i] + b[i];
}

// ===================== launch =====================
extern "C" void kernel_launch(void* const* d_in, const int* in_sizes, int n_in,
                              void* d_out, int out_size, void* d_ws, size_t ws_size,
                              hipStream_t stream) {
  const int*   positions = (const int*)d_in[0];
  const float* hs     = (const float*)d_in[1];
  const float* rsd    = (const float*)d_in[2];
  const float* w_in   = (const float*)d_in[3];
  const float* w_post = (const float*)d_in[4];
  const float* w_s1   = (const float*)d_in[5];
  const float* w_qln  = (const float*)d_in[6];
  const float* w_kvln = (const float*)d_in[7];
  const float* iklnw  = (const float*)d_in[8];
  const float* iklnb  = (const float*)d_in[9];
  const float* w_s3   = (const float*)d_in[10];
  const float* wukt   = (const float*)d_in[11];
  const float* wuv    = (const float*)d_in[12];
  const float* w_o    = (const float*)d_in[13];
  const float* gate_w = (const float*)d_in[14];
  const float* gate_b = (const float*)d_in[15];
  const float* sh_gu  = (const float*)d_in[16];
  const float* sh_dn  = (const float*)d_in[17];
  const float* ex_gu  = (const float*)d_in[18];
  const float* ex_dn  = (const float*)d_in[19];

  float* ws = (float*)d_ws;
  typedef unsigned short ush;
  // -------- workspace layout (float units), phase-disjoint aliasing; max 32,808,960 f = 131.2 MB --------
  float* RES   = ws + 0;          // 2,097,152
  float* COSB  = ws + 2097152;    // 32,768
  float* SINB  = ws + 2129920;    // 32,768
  float* KVC   = ws + 2162688;    // 524,288
  float* KPE   = ws + 2686976;    // 65,536
  float* IDXK  = ws + 2752512;    // 131,072
  float* IDXW  = ws + 2883584;    // 32,768
  float* COMB  = ws + 2916352;    // 8,192
  // phase A
  ush*   HB    = (ush*)(ws + 2924544);   // 2,097,152 ush
  ush*   WS1B  = (ush*)(ws + 3973120);   // 3,145,728 ush (1536x2048 padded)
  float* S1    = ws + 5545984;           // 1,540,096
  ush*   QCB   = (ush*)(ws + 7086080);   // 786,432 ush
  ush*   WS3B  = (ush*)(ws + 7479296);   // 5,505,024 ush
  ush*   WOB   = (ush*)(ws + 7479296);   // alias WS3B; converted AFTER s3 GEMM
  float* S3    = ws + 10231808;          // 7,340,032
  float* ATTN  = ws + 10231808;          // alias S3 (S3 f32 dead after S3B conversion)
  ush*   S3B   = (ush*)(ws + 17571840);  // 7,340,032 ush
  ush*   WUKTB = (ush*)(ws + 21241856);  // 1,048,576 ush
  ush*   QLNB  = (ush*)(ws + 21766144);  // 8,388,608 ush
  float* ISC   = ws + 25960448;          // 524,288
  unsigned char* MASK = (unsigned char*)(ws + 26484736); // 1,048,576 B
  ush*   WUVB  = (ush*)(ws + 26746880);  // 1,048,576 ush
  ush*   OBUFB = (ush*)(ws + 27271168);  // 8,388,608 ush
  ush*   O2B   = (ush*)(ws + 31465472);  // 2,097,152 ush
  // phase B (all written after k_res2)
  float* H2     = ws + 2924544;          // 2,097,152 (alias HB)
  ush*   H2B    = (ush*)(ws + 5021696);  // 2,097,152 ush
  ush*   SHGUB  = (ush*)(ws + 6070272);  // 2,097,152 ush
  ush*   SHDNB  = (ush*)(ws + 7118848);  // 1,048,576 ush
  ush*   EXGUB  = (ush*)(ws + 7643136);  // 16,777,216 ush
  ush*   EXDNB  = (ush*)(ws + 16031744); // 8,388,608 ush
  float* GUS8   = ws + 20226048;         // 8,388,608
  float* GUSsh  = ws + 20226048;         // alias (consumed before MoE gu)
  ush*   SHACTB = (ush*)(ws + 21274624); // 524,288 ush (inside GUS8, time-disjoint)
  ush*   ACTB8  = (ush*)(ws + 28614656); // 4,194,304 ush
  float* SHARED = ws + 30711808;         // 2,097,152
  float* ROUTED = ws + 0;                // alias RES (dead after res2)

  float* OUT0 = (float*)d_out;
  float* OUT_RES2 = OUT0 + (size_t)TT*HID;

  // 1. prelude
  k_prelude<<<TT, 256, 0, stream>>>(hs, rsd, w_in, RES, HB);
  k_ropecs<<<(TT*32)/256, 256, 0, stream>>>(positions, COSB, SINB);
  // 2. early weight conversions
  k_f2b<<<1024, 256, 0, stream>>>(w_s1, WS1B, 3080192LL, 3145728LL);  // pad rows 1504..1535 = 0
  k_f2b<<<1024, 256, 0, stream>>>(w_s3, WS3B, 5505024LL, 5505024LL);
  k_tconvb<<<dim3(16,4,16), 256, 0, stream>>>(wukt, WUKTB, 128, 512);
  k_tconvb<<<dim3(4,16,16), 256, 0, stream>>>(wuv, WUVB, 512, 128);
  // 3. s1 = h @ w_s1^T
  k_mgemm<false><<<dim3(12,8,1), 256, 0, stream>>>(HB, 2048, 0, WS1B, 2048, 0, S1, S1W, 0, 1504, 2048, 1, 0, 0);
  // 4. post-s1
  k_post1<<<TT, 256, 0, stream>>>(S1, w_qln, w_kvln, iklnw, iklnb, COSB, SINB, QCB, KVC, KPE, IDXK, IDXW);
  // 5. s3 = q_c @ w_s3^T
  k_mgemm<false><<<dim3(56,8,1), 256, 0, stream>>>(QCB, 768, 0, WS3B, 768, 0, S3, S3W, 0, S3W, 768, 1, 0, 0);
  // 6. post-s3 + convert s3 -> bf16 ; convert w_o (into WS3B slot, now dead)
  k_post3<<<TT, 256, 0, stream>>>(S3, COSB, SINB);
  k_f2b<<<1024, 256, 0, stream>>>(S3, S3B, 7340032LL, 7340032LL);
  k_f2b<<<1024, 256, 0, stream>>>(w_o, WOB, 4194304LL, 4194304LL);
  // 7. ql_nope (batched heads) -> bf16
  k_mgemm<true><<<dim3(4,8,16), 256, 0, stream>>>(S3B + 4096, S3W, 192, WUKTB, 128, 65536, QLNB, 8192, 512, 512, 128, 1, 0, 0);
  // 8-9. indexer + top-512
  k_iscores<<<dim3(16,512), 256, 0, stream>>>(S3B, IDXK, IDXW, ISC);
  k_topk<<<512, 512, 0, stream>>>(ISC, MASK);
  // 10. attention -> bf16 o
  k_attn<<<dim3(TT,2), 256, 0, stream>>>(QLNB, S3B, KVC, KPE, MASK, OBUFB);
  // 11. o2 = o @ W_UV (batched heads) -> bf16
  k_mgemm<true><<<dim3(1,8,16), 256, 0, stream>>>(OBUFB, 8192, 512, WUVB, 512, 65536, O2B, 2048, 128, 128, 512, 1, 0, 0);
  // 12. attn_out = o2 @ w_o^T
  k_mgemm<false><<<dim3(16,8,1), 256, 0, stream>>>(O2B, 2048, 0, WOB, 2048, 0, ATTN, 2048, 0, 2048, 2048, 1, 0, 0);
  // 13. res2 + h2
  k_res2<<<TT, 256, 0, stream>>>(ATTN, RES, w_post, OUT_RES2, H2, H2B);
  // 14. routing (f32)
  k_gate<<<TT, 256, 0, stream>>>(H2, gate_w, gate_b, COMB);
  // 15. late weight conversions
  k_f2b<<<1024, 256, 0, stream>>>(sh_gu, SHGUB, 2097152LL, 2097152LL);
  k_f2b<<<1024, 256, 0, stream>>>(sh_dn, SHDNB, 1048576LL, 1048576LL);
  k_f2b<<<1024, 256, 0, stream>>>(ex_gu, EXGUB, 16777216LL, 16777216LL);
  k_f2b<<<1024, 256, 0, stream>>>(ex_dn, EXDNB, 8388608LL, 8388608LL);
  // 16. shared expert
  k_mgemm<false><<<dim3(8,8,1), 256, 0, stream>>>(H2B, 2048, 0, SHGUB, 2048, 0, GUSsh, 1024, 0, 1024, 2048, 1, 0, 0);
  k_swiglu_sh<<<2048, 256, 0, stream>>>(GUSsh, SHACTB);
  k_mgemm<false><<<dim3(16,8,1), 256, 0, stream>>>(SHACTB, 512, 0, SHDNB, 512, 0, SHARED, 2048, 0, 2048, 512, 1, 0, 0);
  // 17. MoE: gate-up batched over experts; swiglu with comb folded; down folded over 8 expert segments
  k_mgemm<false><<<dim3(8,8,8), 256, 0, stream>>>(H2B, 2048, 0, EXGUB, 2048, 2097152, GUS8, 1024, 1048576, 1024, 2048, 1, 0, 0);
  k_swiglu8<<<16384, 256, 0, stream>>>(GUS8, COMB, ACTB8);
  k_mgemm<false><<<dim3(16,8,1), 256, 0, stream>>>(ACTB8, 512, 0, EXDNB, 512, 0, ROUTED, 2048, 0, 2048, 512, 8, 524288, 1048576);
  // 18. out = shared + routed
  k_add<<<(TT*HID)/256, 256, 0, stream>>>(SHARED, ROUTED, OUT0);
}

// Round 3
// 651.651 us; speedup vs baseline: 7.4539x; 2.6635x over previous
//
#include <hip/hip_runtime.h>
#include <math.h>

// ===================== constants =====================
static constexpr int TT  = 1024;
static constexpr int HID = 2048;
static constexpr int NH  = 16;
static constexpr int QL  = 768;
static constexpr int KVL = 512;
static constexpr int RD  = 64;     // rope dim
static constexpr int IH  = 32;     // idx heads
static constexpr int ID  = 128;    // idx dim
static constexpr int S1W = QL + KVL + RD + ID + IH;   // 1504
static constexpr int S3W = IH*ID + NH*(128+RD);       // 7168

#define SCALE_ATT 0.07216878364870323f   // 1/sqrt(192)
#define SC_IDXQ   0.08838834764831845f   // 1/sqrt(128)
#define SC_IDXW   0.17677669529663687f   // 1/sqrt(32)
#define NEGR      -1e30f
#define NEGL      -3.0e38f

typedef __bf16 bf16x8 __attribute__((ext_vector_type(8)));
typedef float  f32x4  __attribute__((ext_vector_type(4)));

// bf16 <-> f32 helpers (RNE)
__device__ __forceinline__ unsigned short f2b(float x) {
  union { float f; unsigned u; } v; v.f = x;
  unsigned r = v.u + 0x7FFFu + ((v.u >> 16) & 1u);
  return (unsigned short)(r >> 16);
}
__device__ __forceinline__ float b2f(unsigned short u) {
  union { unsigned u; float f; } v; v.u = ((unsigned)u) << 16;
  return v.f;
}

// ===================== helpers =====================
__device__ __forceinline__ float blk_sum256(float v, float* s) {
  #pragma unroll
  for (int o = 32; o > 0; o >>= 1) v += __shfl_down(v, o, 64);
  __syncthreads();
  if ((threadIdx.x & 63) == 0) s[threadIdx.x >> 6] = v;
  __syncthreads();
  return s[0] + s[1] + s[2] + s[3];
}

// ===================== prelude: res = hs+resid; hb = bf16(rms(res)*w) =====================
__global__ __launch_bounds__(256) void k_prelude(const float* __restrict__ hs,
                                                 const float* __restrict__ rsd,
                                                 const float* __restrict__ w,
                                                 float* __restrict__ res,
                                                 unsigned short* __restrict__ hb) {
  int t = blockIdx.x;
  __shared__ float scr[4];
  float vals[8]; float ss = 0.f;
  #pragma unroll
  for (int r = 0; r < 8; r++) {
    int d = threadIdx.x + 256*r;
    float v = hs[(size_t)t*HID + d] + rsd[(size_t)t*HID + d];
    vals[r] = v; res[(size_t)t*HID + d] = v; ss = fmaf(v, v, ss);
  }
  ss = blk_sum256(ss, scr);
  float inv = 1.f/sqrtf(ss/(float)HID + 1e-6f);
  #pragma unroll
  for (int r = 0; r < 8; r++) {
    int d = threadIdx.x + 256*r;
    hb[(size_t)t*HID + d] = f2b(vals[r]*inv*w[d]);
  }
}

// res2 = attn + res -> d_out; h2 f32 + h2 bf16
__global__ __launch_bounds__(256) void k_res2(const float* __restrict__ attn,
                                              const float* __restrict__ res,
                                              const float* __restrict__ w,
                                              float* __restrict__ res2_out,
                                              float* __restrict__ h2,
                                              unsigned short* __restrict__ h2b) {
  int t = blockIdx.x;
  __shared__ float scr[4];
  float vals[8]; float ss = 0.f;
  #pragma unroll
  for (int r = 0; r < 8; r++) {
    int d = threadIdx.x + 256*r;
    float v = attn[(size_t)t*HID + d] + res[(size_t)t*HID + d];
    vals[r] = v; res2_out[(size_t)t*HID + d] = v; ss = fmaf(v, v, ss);
  }
  ss = blk_sum256(ss, scr);
  float inv = 1.f/sqrtf(ss/(float)HID + 1e-6f);
  #pragma unroll
  for (int r = 0; r < 8; r++) {
    int d = threadIdx.x + 256*r;
    float o = vals[r]*inv*w[d];
    h2[(size_t)t*HID + d] = o;
    h2b[(size_t)t*HID + d] = f2b(o);
  }
}

// ===================== rope cos/sin tables (fp64 internally) =====================
__global__ void k_ropecs(const int* __restrict__ pos, float* __restrict__ cosb, float* __restrict__ sinb) {
  int i = blockIdx.x*256 + threadIdx.x;
  if (i >= TT*32) return;
  int t = i >> 5, k = i & 31;
  double inv = pow(10000.0, -((double)(2*k))/64.0);
  double f = (double)pos[t] * inv;
  cosb[i] = (float)cos(f);
  sinb[i] = (float)sin(f);
}

// ===================== f32 -> bf16 convert (with zero tail pad) =====================
__global__ void k_f2b(const float* __restrict__ s, unsigned short* __restrict__ d,
                      long long n, long long ntot) {
  long long stride = (long long)gridDim.x * 1024;
  for (long long i = ((long long)blockIdx.x*256 + threadIdx.x)*4; i < ntot; i += stride) {
    float x0, x1, x2, x3;
    if (i + 3 < n) { float4 v = *(const float4*)(s + i); x0=v.x; x1=v.y; x2=v.z; x3=v.w; }
    else {
      x0 = (i   < n) ? s[i]   : 0.f; x1 = (i+1 < n) ? s[i+1] : 0.f;
      x2 = (i+2 < n) ? s[i+2] : 0.f; x3 = (i+3 < n) ? s[i+3] : 0.f;
    }
    ushort4 o; o.x=f2b(x0); o.y=f2b(x1); o.z=f2b(x2); o.w=f2b(x3);
    *(ushort4*)(d + i) = o;
  }
}

// ===================== transpose + convert: src (R,C) f32 -> dst (C,R) bf16, batched z =====================
__global__ __launch_bounds__(256) void k_tconvb(const float* __restrict__ src,
                                                unsigned short* __restrict__ dst,
                                                int R, int C) {
  src += (size_t)blockIdx.z * R * C;
  dst += (size_t)blockIdx.z * R * C;
  __shared__ float tile[32][33];
  int c0 = blockIdx.x * 32, r0 = blockIdx.y * 32;
  int tx = threadIdx.x & 31, ty = threadIdx.x >> 5;
  #pragma unroll
  for (int i = 0; i < 4; i++) {
    int r = r0 + ty + i*8;
    tile[ty + i*8][tx] = src[(size_t)r*C + c0 + tx];
  }
  __syncthreads();
  #pragma unroll
  for (int i = 0; i < 4; i++) {
    int c = c0 + ty + i*8;
    dst[(size_t)c*R + r0 + tx] = f2b(tile[tx][ty + i*8]);
  }
}

// ===================== MFMA bf16 GEMM: C(M,N) = alpha * A(M,K) @ B(N,K)^T =====================
// A,B bf16 (ushort). 128x128 tile, 4 waves (2x2), BK=64, XOR-swizzled LDS.
// M multiple of 128; B rows valid to N tiles (grid-exact); C write guarded n<N.
// nseg>1: accumulate over segments (A += segA, B += segB per segment) — used for MoE down.
template<bool STORE_BF16>
__global__ __launch_bounds__(256) void k_mgemm(const unsigned short* __restrict__ A, int lda, long long sA,
                                               const unsigned short* __restrict__ B, int ldb, long long sB,
                                               void* __restrict__ Cv, int ldc, long long sC,
                                               int N, int K, float alpha,
                                               int nseg, long long segA, long long segB) {
  __shared__ __align__(16) unsigned short As[128*64];
  __shared__ __align__(16) unsigned short Bs[128*64];
  const int tid  = threadIdx.x;
  const int wave = tid >> 6, lane = tid & 63;
  const int wm = wave >> 1, wn = wave & 1;
  const int row0 = blockIdx.y * 128;
  const int col0 = blockIdx.x * 128;
  A += (size_t)blockIdx.z * (size_t)sA;
  B += (size_t)blockIdx.z * (size_t)sB;

  f32x4 acc[4][4] = {};

  const int l15 = lane & 15, l4 = lane >> 4;
  const int sx = l15 & 7;

  for (int seg = 0; seg < nseg; seg++) {
    const unsigned short* Ab = A + (size_t)seg * segA;
    const unsigned short* Bb = B + (size_t)seg * segB;
    for (int k0 = 0; k0 < K; k0 += 64) {
      __syncthreads();
      #pragma unroll
      for (int it = 0; it < 4; it++) {
        int sidx = tid + 256*it;          // 0..1023 (128 rows x 8 slots)
        int r = sidx >> 3, s = sidx & 7;
        int ldsoff = r*64 + ((s ^ (r & 7)) << 3);
        uint4 va = *(const uint4*)(Ab + (size_t)(row0 + r)*lda + k0 + s*8);
        *(uint4*)&As[ldsoff] = va;
        uint4 vb = *(const uint4*)(Bb + (size_t)(col0 + r)*ldb + k0 + s*8);
        *(uint4*)&Bs[ldsoff] = vb;
      }
      __syncthreads();
      #pragma unroll
      for (int kc = 0; kc < 2; kc++) {
        const int sl = ((kc*4 + l4) ^ sx) << 3;
        bf16x8 fa[4], fb[4];
        #pragma unroll
        for (int mf = 0; mf < 4; mf++)
          fa[mf] = *(const bf16x8*)&As[(wm*64 + mf*16 + l15)*64 + sl];
        #pragma unroll
        for (int nf = 0; nf < 4; nf++)
          fb[nf] = *(const bf16x8*)&Bs[(wn*64 + nf*16 + l15)*64 + sl];
        #pragma unroll
        for (int mf = 0; mf < 4; mf++)
          #pragma unroll
          for (int nf = 0; nf < 4; nf++)
            acc[mf][nf] = __builtin_amdgcn_mfma_f32_16x16x32_bf16(fa[mf], fb[nf], acc[mf][nf], 0, 0, 0);
      }
    }
  }

  // C write: col = lane&15, row = (lane>>4)*4 + reg  [m89-verified]
  #pragma unroll
  for (int mf = 0; mf < 4; mf++) {
    #pragma unroll
    for (int nf = 0; nf < 4; nf++) {
      int n = col0 + wn*64 + nf*16 + l15;
      if (n < N) {
        #pragma unroll
        for (int r = 0; r < 4; r++) {
          int m = row0 + wm*64 + mf*16 + l4*4 + r;
          size_t idx = (size_t)m*ldc + n;
          float v = acc[mf][nf][r] * alpha;
          if (STORE_BF16) ((unsigned short*)Cv)[(size_t)blockIdx.z*sC + idx] = f2b(v);
          else            ((float*)Cv)[(size_t)blockIdx.z*sC + idx] = v;
        }
      }
    }
  }
}

// ===================== post-s1 =====================
__global__ __launch_bounds__(256) void k_post1(const float* __restrict__ s1,
    const float* __restrict__ wq, const float* __restrict__ wkv,
    const float* __restrict__ lnw, const float* __restrict__ lnb,
    const float* __restrict__ cosb, const float* __restrict__ sinb,
    unsigned short* __restrict__ qcb, float* __restrict__ kvc, float* __restrict__ kpe,
    float* __restrict__ idxk, float* __restrict__ idxw) {
  int t = blockIdx.x, tid = threadIdx.x;
  const float* row = s1 + (size_t)t*S1W;
  __shared__ float scr[4];
  __shared__ float yb[128];
  float ss = 0.f;
  for (int d = tid; d < QL; d += 256) { float v = row[d]; ss = fmaf(v,v,ss); }
  ss = blk_sum256(ss, scr);
  float inv = 1.f/sqrtf(ss/(float)QL + 1e-6f);
  for (int d = tid; d < QL; d += 256) qcb[(size_t)t*QL + d] = f2b(row[d]*inv*wq[d]);
  ss = 0.f;
  for (int d = tid; d < KVL; d += 256) { float v = row[QL+d]; ss = fmaf(v,v,ss); }
  ss = blk_sum256(ss, scr);
  inv = 1.f/sqrtf(ss/(float)KVL + 1e-6f);
  for (int d = tid; d < KVL; d += 256) kvc[(size_t)t*KVL + d] = row[QL+d]*inv*wkv[d];
  float sm = (tid < 128) ? row[1344 + tid] : 0.f;
  float tot = blk_sum256(sm, scr);
  float mean = tot / 128.f;
  float vs = 0.f;
  if (tid < 128) { float v = row[1344+tid] - mean; vs = v*v; }
  vs = blk_sum256(vs, scr);
  float ivn = 1.f/sqrtf(vs/128.f + 1e-6f);
  if (tid < 128) yb[tid] = (row[1344+tid]-mean)*ivn*lnw[tid] + lnb[tid];
  __syncthreads();
  if (tid < 32) {
    float c = cosb[t*32 + tid], s = sinb[t*32 + tid];
    idxk[(size_t)t*ID + tid]      = yb[tid]*c - yb[32+tid]*s;
    idxk[(size_t)t*ID + 32 + tid] = yb[32+tid]*c + yb[tid]*s;
    float x1 = row[1280+tid], x2 = row[1312+tid];
    kpe[(size_t)t*RD + tid]      = x1*c - x2*s;
    kpe[(size_t)t*RD + 32 + tid] = x2*c + x1*s;
    idxw[(size_t)t*IH + tid] = row[1472+tid] * SC_IDXW;
  } else if (tid >= 64 && tid < 128) {
    idxk[(size_t)t*ID + tid] = yb[tid];
  }
}

// ===================== post-s3 (in place f32) =====================
__global__ __launch_bounds__(256) void k_post3(float* __restrict__ s3,
                                               const float* __restrict__ cosb,
                                               const float* __restrict__ sinb) {
  int t = blockIdx.x, tid = threadIdx.x;
  float* row = s3 + (size_t)t*S3W;
  const float* cr = cosb + t*32; const float* sr = sinb + t*32;
  for (int p = tid; p < 1024; p += 256) {
    int h = p >> 5, d = p & 31;
    float c = cr[d], s = sr[d];
    float x1 = row[h*ID + d], x2 = row[h*ID + 32 + d];
    row[h*ID + d]      = (x1*c - x2*s) * SC_IDXQ;
    row[h*ID + 32 + d] = (x2*c + x1*s) * SC_IDXQ;
  }
  for (int p = tid; p < 2048; p += 256) {
    int h = p >> 6, d = 64 + (p & 63);
    row[h*ID + d] *= SC_IDXQ;
  }
  for (int p = tid; p < 512; p += 256) {
    int h = p >> 5, d = p & 31;
    float c = cr[d], s = sr[d];
    int base = IH*ID + h*192 + 128;
    float x1 = row[base + d], x2 = row[base + 32 + d];
    row[base + d]      = x1*c - x2*s;
    row[base + 32 + d] = x2*c + x1*s;
  }
}

// ===================== q_pe gather into QMQA concat layout (scaled) =====================
__global__ void k_qpe(const unsigned short* __restrict__ s3b, unsigned short* __restrict__ qm) {
  int i = blockIdx.x*256 + threadIdx.x;   // < 1024*16*64
  int t = i >> 10, r = i & 1023;
  int h = r >> 6, j = r & 63;
  float v = b2f(s3b[(size_t)t*S3W + IH*ID + h*192 + 128 + j]) * SCALE_ATT;
  qm[(size_t)t*9216 + h*576 + 512 + j] = f2b(v);
}

// ===================== kv concat bf16 =====================
__global__ void k_kvb(const float* __restrict__ kvc, const float* __restrict__ kpe,
                      unsigned short* __restrict__ kvb) {
  int i = blockIdx.x*256 + threadIdx.x;   // < 1024*576
  int s = i / 576, d = i - s*576;
  float v = (d < 512) ? kvc[(size_t)s*KVL + d] : kpe[(size_t)s*RD + (d - 512)];
  kvb[i] = f2b(v);
}

// ===================== indexer scores (rows t>=512 only) =====================
__global__ __launch_bounds__(256) void k_iscores(const unsigned short* __restrict__ s3b,
                                                 const float* __restrict__ idxk,
                                                 const float* __restrict__ idxw,
                                                 float* __restrict__ isc) {
  int t = 512 + blockIdx.y;
  int s0 = blockIdx.x * 64;
  int tid = threadIdx.x;
  float* out = isc + (size_t)(t - 512) * TT;
  if (s0 > t) {
    if (tid < 64) out[s0 + tid] = NEGR;
    return;
  }
  __shared__ __align__(16) float q_lds[32*128];
  __shared__ __align__(16) float k_lds[64*128];
  __shared__ float w_lds[32];
  __shared__ float part[4][64];
  for (int e = tid; e < 4096; e += 256) q_lds[e] = b2f(s3b[(size_t)t*S3W + e]);
  for (int e = tid; e < 8192; e += 256) {
    int sl = e >> 7, d = e & 127;
    int p4 = (d >> 2) ^ (sl & 31);
    k_lds[sl*128 + p4*4 + (d & 3)] = idxk[(size_t)(s0 + sl)*ID + d];
  }
  if (tid < 32) w_lds[tid] = idxw[t*IH + tid];
  __syncthreads();
  int sl = tid & 63, hq = tid >> 6;
  float acc = 0.f;
  #pragma unroll 1
  for (int hh = 0; hh < 8; hh++) {
    int h = hq*8 + hh;
    const float4* qrow = (const float4*)(q_lds + h*128);
    const float4* krow = (const float4*)(k_lds + sl*128);
    float dx=0.f, dy=0.f, dz=0.f, dw=0.f;
    #pragma unroll
    for (int q4 = 0; q4 < 32; q4++) {
      float4 qa = qrow[q4];
      float4 ka = krow[q4 ^ (sl & 31)];
      dx = fmaf(qa.x, ka.x, dx); dy = fmaf(qa.y, ka.y, dy);
      dz = fmaf(qa.z, ka.z, dz); dw = fmaf(qa.w, ka.w, dw);
    }
    float dot = (dx+dy)+(dz+dw);
    acc += fmaxf(dot, 0.f) * w_lds[h];
  }
  part[hq][sl] = acc;
  __syncthreads();
  if (tid < 64) {
    int s_g = s0 + tid;
    float v = part[0][tid] + part[1][tid] + part[2][tid] + part[3][tid];
    out[s_g] = (s_g <= t) ? v : NEGR;
  }
}

// ===================== exact per-row top-512 (bitonic, tie -> lower index) =====================
__global__ __launch_bounds__(512) void k_topk(const float* __restrict__ isc,
                                              unsigned char* __restrict__ mask) {
  int t = 512 + blockIdx.x;
  const float* row = isc + (size_t)blockIdx.x * TT;
  __shared__ unsigned long long keys[1024];
  int tid = threadIdx.x;
  for (int i = tid; i < 1024; i += 512) {
    float v = row[i];
    unsigned int b = __float_as_uint(v);
    unsigned int u = (b & 0x80000000u) ? ~b : (b | 0x80000000u);
    keys[i] = ((unsigned long long)u << 32) | (unsigned int)(1023 - i);
  }
  __syncthreads();
  for (int k = 2; k <= 1024; k <<= 1) {
    for (int j = k >> 1; j > 0; j >>= 1) {
      int i = ((tid & ~(j - 1)) << 1) | (tid & (j - 1));
      int l = i | j;
      unsigned long long a = keys[i], b = keys[l];
      bool up = ((i & k) == 0);
      if ((a < b) == up) { keys[i] = b; keys[l] = a; }
      __syncthreads();
    }
  }
  unsigned char* mrow = mask + (size_t)t * TT;
  for (int p = tid; p < 1024; p += 512) {
    int s = 1023 - (int)(keys[p] & 0xFFFFFFFFu);
    mrow[s] = (p < 512) ? (unsigned char)1 : (unsigned char)0;
  }
}

// ===================== masked softmax over P rows (in place, bf16) =====================
__global__ __launch_bounds__(256) void k_psoft(unsigned short* __restrict__ pb,
                                               const unsigned char* __restrict__ mask) {
  int b = blockIdx.x;
  int t = b & 1023, h = b >> 10;
  unsigned short* row = pb + ((size_t)h << 20) + ((size_t)t << 10);
  int tid = threadIdx.x;
  __shared__ float scr[4];
  int s0 = tid * 4;
  ushort4 raw = *(const ushort4*)(row + s0);
  float v0 = b2f(raw.x), v1 = b2f(raw.y), v2 = b2f(raw.z), v3 = b2f(raw.w);
  bool m0, m1, m2, m3;
  if (t < 512) {
    m0 = (s0 <= t); m1 = (s0+1 <= t); m2 = (s0+2 <= t); m3 = (s0+3 <= t);
  } else {
    uchar4 mk = *(const uchar4*)(mask + (size_t)t*TT + s0);
    m0 = (s0 <= t) && mk.x; m1 = (s0+1 <= t) && mk.y;
    m2 = (s0+2 <= t) && mk.z; m3 = (s0+3 <= t) && mk.w;
  }
  float mx = NEGL;
  if (m0) mx = v0;
  if (m1) mx = fmaxf(mx, v1);
  if (m2) mx = fmaxf(mx, v2);
  if (m3) mx = fmaxf(mx, v3);
  #pragma unroll
  for (int o = 32; o > 0; o >>= 1) mx = fmaxf(mx, __shfl_down(mx, o, 64));
  __syncthreads();
  if ((tid & 63) == 0) scr[tid >> 6] = mx;
  __syncthreads();
  mx = fmaxf(fmaxf(scr[0], scr[1]), fmaxf(scr[2], scr[3]));
  float p0 = m0 ? expf(v0 - mx) : 0.f;
  float p1 = m1 ? expf(v1 - mx) : 0.f;
  float p2 = m2 ? expf(v2 - mx) : 0.f;
  float p3 = m3 ? expf(v3 - mx) : 0.f;
  float sum = blk_sum256((p0+p1)+(p2+p3), scr);
  float inv = 1.f / sum;
  ushort4 o;
  o.x = f2b(p0*inv); o.y = f2b(p1*inv); o.z = f2b(p2*inv); o.w = f2b(p3*inv);
  *(ushort4*)(row + s0) = o;
}

// ===================== gating / routing (f32 exact) =====================
__global__ __launch_bounds__(256) void k_gate(const float* __restrict__ h2,
                                              const float* __restrict__ gw,
                                              const float* __restrict__ gb,
                                              float* __restrict__ comb) {
  int t = blockIdx.x, tid = threadIdx.x;
  int e = tid >> 5, lane = tid & 31;
  __shared__ float gl[8];
  float p = 0.f;
  for (int d = lane; d < HID; d += 32) p = fmaf(h2[(size_t)t*HID+d], gw[(size_t)e*HID+d], p);
  #pragma unroll
  for (int o = 16; o > 0; o >>= 1) p += __shfl_down(p, o, 32);
  if (lane == 0) gl[e] = p;
  __syncthreads();
  if (tid == 0) {
    float sg[8], sc[8];
    #pragma unroll
    for (int i = 0; i < 8; i++) { sg[i] = 1.f/(1.f+expf(-gl[i])); sc[i] = sg[i] + gb[i]; }
    float gs[4];
    #pragma unroll
    for (int g = 0; g < 4; g++) gs[g] = sc[2*g] + sc[2*g+1];
    int g0 = 0;
    for (int g = 1; g < 4; g++) if (gs[g] > gs[g0]) g0 = g;
    int g1 = -1;
    for (int g = 0; g < 4; g++) { if (g == g0) continue; if (g1 < 0 || gs[g] > gs[g1]) g1 = g; }
    float wsum = 1e-20f;
    #pragma unroll
    for (int i = 0; i < 8; i++) { int g = i >> 1; if (g == g0 || g == g1) wsum += sg[i]; }
    #pragma unroll
    for (int i = 0; i < 8; i++) { int g = i >> 1; comb[t*8+i] = (g == g0 || g == g1) ? sg[i]/wsum*2.5f : 0.f; }
  }
}

// ===================== swiglu variants =====================
__global__ void k_swiglu_sh(const float* __restrict__ gus, unsigned short* __restrict__ act) {
  int i = blockIdx.x*256 + threadIdx.x;   // < 1024*512
  int t = i >> 9, c = i & 511;
  float g = gus[(size_t)t*1024 + c], u = gus[(size_t)t*1024 + 512 + c];
  act[i] = f2b(g/(1.f + expf(-g)) * u);
}
__global__ void k_swiglu8(const float* __restrict__ gus8, const float* __restrict__ comb,
                          unsigned short* __restrict__ act8) {
  long long i = (long long)blockIdx.x*256 + threadIdx.x;  // < 8*1024*512
  int e = (int)(i >> 19);
  int rem = (int)(i & 524287);
  int t = rem >> 9, c = rem & 511;
  const float* g0 = gus8 + (size_t)e*1048576 + (size_t)t*1024;
  float g = g0[c], u = g0[512 + c];
  act8[i] = f2b(g/(1.f + expf(-g)) * u * comb[t*8 + e]);
}

__global__ void k_add(const float* __restrict__ a, const float* __restrict__ b, float* __restrict__ o) {
  int i = blockIdx.x*256 + threadIdx.x;
  o[i] = a[i] + b[i];
}

// ===================== launch =====================
extern "C" void kernel_launch(void* const* d_in, const int* in_sizes, int n_in,
                              void* d_out, int out_size, void* d_ws, size_t ws_size,
                              hipStream_t stream) {
  const int*   positions = (const int*)d_in[0];
  const float* hs     = (const float*)d_in[1];
  const float* rsd    = (const float*)d_in[2];
  const float* w_in   = (const float*)d_in[3];
  const float* w_post = (const float*)d_in[4];
  const float* w_s1   = (const float*)d_in[5];
  const float* w_qln  = (const float*)d_in[6];
  const float* w_kvln = (const float*)d_in[7];
  const float* iklnw  = (const float*)d_in[8];
  const float* iklnb  = (const float*)d_in[9];
  const float* w_s3   = (const float*)d_in[10];
  const float* wukt   = (const float*)d_in[11];
  const float* wuv    = (const float*)d_in[12];
  const float* w_o    = (const float*)d_in[13];
  const float* gate_w = (const float*)d_in[14];
  const float* gate_b = (const float*)d_in[15];
  const float* sh_gu  = (const float*)d_in[16];
  const float* sh_dn  = (const float*)d_in[17];
  const float* ex_gu  = (const float*)d_in[18];
  const float* ex_dn  = (const float*)d_in[19];

  float* ws = (float*)d_ws;
  typedef unsigned short ush;
  // -------- workspace layout (float units), phase-disjoint aliasing; peak 32,808,960 f = 131.2 MB --------
  float* RES   = ws + 0;          // 2,097,152
  float* COSB  = ws + 2097152;    // 32,768
  float* SINB  = ws + 2129920;    // 32,768
  float* KVC   = ws + 2162688;    // 524,288
  float* KPE   = ws + 2686976;    // 65,536
  float* IDXK  = ws + 2752512;    // 131,072
  float* IDXW  = ws + 2883584;    // 32,768
  float* COMB  = ws + 2916352;    // 8,192
  // phase A
  ush*   HB    = (ush*)(ws + 2924544);   // 2,097,152 ush
  ush*   WS1B  = (ush*)(ws + 3973120);   // 3,145,728 ush (1536x2048 padded)
  float* S1    = ws + 5545984;           // 1,540,096
  ush*   QCB   = (ush*)(ws + 7086080);   // 786,432 ush
  ush*   WS3B  = (ush*)(ws + 7479296);   // 5,505,024 ush
  ush*   WOB   = (ush*)(ws + 7479296);   // alias WS3B; converted AFTER s3 GEMM
  float* S3    = ws + 10231808;          // 7,340,032
  ush*   S3B   = (ush*)(ws + 17571840);  // 7,340,032 ush
  ush*   WUKTB = (ush*)(ws + 21241856);  // 1,048,576 ush
  ush*   QMQAB = (ush*)(ws + 21766144);  // 9,437,184 ush : [t][h][576], ends 26,484,736
  float* ISC   = ws + 26484736;          // 524,288
  unsigned char* MASK = (unsigned char*)(ws + 27009024); // 1,048,576 B
  ush*   WUVB  = (ush*)(ws + 27271168);  // 1,048,576 ush
  ush*   KVB   = (ush*)(ws + 27795456);  // 589,824 ush (pad to 294,912 f)
  ush*   VTB   = (ush*)(ws + 28090368);  // 524,288 ush : V^T (512,1024)
  ush*   O2B   = (ush*)(ws + 28352512);  // 2,097,152 ush
  ush*   PB    = (ush*)(ws + 10231808);  // 16,777,216 ush : [h][t][1024]; overlays dead S3 f32 + S3B head
  ush*   OHB   = (ush*)(ws + 18620416);  // 8,388,608 ush : [h][t][512]; overlays dead S3B tail/WUKTB/QMQAB head
  float* ATTN  = ws + 10231808;          // overlays dead PB
  // phase B (all written after k_res2)
  float* H2     = ws + 2924544;          // 2,097,152 (alias HB)
  ush*   H2B    = (ush*)(ws + 5021696);  // 2,097,152 ush
  ush*   SHGUB  = (ush*)(ws + 6070272);  // 2,097,152 ush
  ush*   SHDNB  = (ush*)(ws + 7118848);  // 1,048,576 ush
  ush*   EXGUB  = (ush*)(ws + 7643136);  // 16,777,216 ush
  ush*   EXDNB  = (ush*)(ws + 16031744); // 8,388,608 ush
  float* GUS8   = ws + 20226048;         // 8,388,608
  float* GUSsh  = ws + 20226048;         // alias (consumed before MoE gu)
  ush*   SHACTB = (ush*)(ws + 21274624); // 524,288 ush (inside GUS8, time-disjoint)
  ush*   ACTB8  = (ush*)(ws + 28614656); // 4,194,304 ush
  float* SHARED = ws + 30711808;         // 2,097,152
  float* ROUTED = ws + 0;                // alias RES (dead after res2)

  float* OUT0 = (float*)d_out;
  float* OUT_RES2 = OUT0 + (size_t)TT*HID;

  // 1. prelude
  k_prelude<<<TT, 256, 0, stream>>>(hs, rsd, w_in, RES, HB);
  k_ropecs<<<(TT*32)/256, 256, 0, stream>>>(positions, COSB, SINB);
  // 2. early weight conversions
  k_f2b<<<1024, 256, 0, stream>>>(w_s1, WS1B, 3080192LL, 3145728LL);  // pad rows 1504..1535 = 0
  k_f2b<<<1024, 256, 0, stream>>>(w_s3, WS3B, 5505024LL, 5505024LL);
  k_tconvb<<<dim3(16,4,16), 256, 0, stream>>>(wukt, WUKTB, 128, 512);
  k_tconvb<<<dim3(4,16,16), 256, 0, stream>>>(wuv, WUVB, 512, 128);
  // 3. s1 = h @ w_s1^T
  k_mgemm<false><<<dim3(12,8,1), 256, 0, stream>>>(HB, 2048, 0, WS1B, 2048, 0, S1, S1W, 0, 1504, 2048, 1.f, 1, 0, 0);
  // 4. post-s1
  k_post1<<<TT, 256, 0, stream>>>(S1, w_qln, w_kvln, iklnw, iklnb, COSB, SINB, QCB, KVC, KPE, IDXK, IDXW);
  // 5. s3 = q_c @ w_s3^T
  k_mgemm<false><<<dim3(56,8,1), 256, 0, stream>>>(QCB, 768, 0, WS3B, 768, 0, S3, S3W, 0, S3W, 768, 1.f, 1, 0, 0);
  // 6. post-s3 + convert s3 -> bf16 ; convert w_o (into WS3B slot, now dead)
  k_post3<<<TT, 256, 0, stream>>>(S3, COSB, SINB);
  k_f2b<<<1024, 256, 0, stream>>>(S3, (ush*)S3B, 7340032LL, 7340032LL);
  k_f2b<<<1024, 256, 0, stream>>>(w_o, WOB, 4194304LL, 4194304LL);
  // 7. ql_nope -> QMQAB[:, :, 0:512] with SCALE_ATT folded; q_pe -> cols 512:576
  k_mgemm<true><<<dim3(4,8,16), 256, 0, stream>>>(S3B + 4096, S3W, 192, WUKTB, 128, 65536, QMQAB, 9216, 576, 512, 128, SCALE_ATT, 1, 0, 0);
  k_qpe<<<4096, 256, 0, stream>>>(S3B, QMQAB);
  // 8-9. indexer + top-512 (read S3B before PB overlays it)
  k_iscores<<<dim3(16,512), 256, 0, stream>>>(S3B, IDXK, IDXW, ISC);
  k_topk<<<512, 512, 0, stream>>>(ISC, MASK);
  // 10. KV concat bf16 + V^T bf16
  k_kvb<<<2304, 256, 0, stream>>>(KVC, KPE, KVB);
  k_tconvb<<<dim3(16,32,1), 256, 0, stream>>>(KVC, VTB, 1024, 512);
  // 11. logits P = Qmqa @ KV^T (per head), pre-scaled -> bf16
  k_mgemm<true><<<dim3(8,8,16), 256, 0, stream>>>(QMQAB, 9216, 576, KVB, 576, 0, PB, 1024, 1048576, 1024, 576, 1.f, 1, 0, 0);
  // 12. masked softmax in place
  k_psoft<<<16384, 256, 0, stream>>>(PB, MASK);
  // 13. O = P @ V (per head) -> OHB [h][t][512] bf16
  k_mgemm<true><<<dim3(4,8,16), 256, 0, stream>>>(PB, 1024, 1048576, VTB, 1024, 0, OHB, 512, 524288, 512, 1024, 1.f, 1, 0, 0);
  // 14. o2 = O @ W_UV (per head) -> O2B [t][h*128]
  k_mgemm<true><<<dim3(1,8,16), 256, 0, stream>>>(OHB, 512, 524288, WUVB, 512, 65536, O2B, 2048, 128, 128, 512, 1.f, 1, 0, 0);
  // 15. attn_out = o2 @ w_o^T
  k_mgemm<false><<<dim3(16,8,1), 256, 0, stream>>>(O2B, 2048, 0, WOB, 2048, 0, ATTN, 2048, 0, 2048, 2048, 1.f, 1, 0, 0);
  // 16. res2 + h2
  k_res2<<<TT, 256, 0, stream>>>(ATTN, RES, w_post, OUT_RES2, H2, H2B);
  // 17. routing (f32)
  k_gate<<<TT, 256, 0, stream>>>(H2, gate_w, gate_b, COMB);
  // 18. late weight conversions
  k_f2b<<<1024, 256, 0, stream>>>(sh_gu, SHGUB, 2097152LL, 2097152LL);
  k_f2b<<<1024, 256, 0, stream>>>(sh_dn, SHDNB, 1048576LL, 1048576LL);
  k_f2b<<<1024, 256, 0, stream>>>(ex_gu, EXGUB, 16777216LL, 16777216LL);
  k_f2b<<<1024, 256, 0, stream>>>(ex_dn, EXDNB, 8388608LL, 8388608LL);
  // 19. shared expert
  k_mgemm<false><<<dim3(8,8,1), 256, 0, stream>>>(H2B, 2048, 0, SHGUB, 2048, 0, GUSsh, 1024, 0, 1024, 2048, 1.f, 1, 0, 0);
  k_swiglu_sh<<<2048, 256, 0, stream>>>(GUSsh, SHACTB);
  k_mgemm<false><<<dim3(16,8,1), 256, 0, stream>>>(SHACTB, 512, 0, SHDNB, 512, 0, SHARED, 2048, 0, 2048, 512, 1.f, 1, 0, 0);
  // 20. MoE: gate-up batched over experts; swiglu with comb folded; down folded over 8 expert segments
  k_mgemm<false><<<dim3(8,8,8), 256, 0, stream>>>(H2B, 2048, 0, EXGUB, 2048, 2097152, GUS8, 1024, 1048576, 1024, 2048, 1.f, 1, 0, 0);
  k_swiglu8<<<16384, 256, 0, stream>>>(GUS8, COMB, ACTB8);
  k_mgemm<false><<<dim3(16,8,1), 256, 0, stream>>>(ACTB8, 512, 0, EXDNB, 512, 0, ROUTED, 2048, 0, 2048, 512, 1.f, 8, 524288, 1048576);
  // 21. out = shared + routed
  k_add<<<(TT*HID)/256, 256, 0, stream>>>(SHARED, ROUTED, OUT0);
}

// Round 4
// 557.291 us; speedup vs baseline: 8.7160x; 1.1693x over previous
//
#include <hip/hip_runtime.h>
#include <math.h>

// ===================== constants =====================
static constexpr int TT  = 1024;
static constexpr int HID = 2048;
static constexpr int NH  = 16;
static constexpr int QL  = 768;
static constexpr int KVL = 512;
static constexpr int RD  = 64;     // rope dim
static constexpr int IH  = 32;     // idx heads
static constexpr int ID  = 128;    // idx dim
static constexpr int S1W = QL + KVL + RD + ID + IH;   // 1504
static constexpr int S3W = IH*ID + NH*(128+RD);       // 7168

#define SCALE_ATT 0.07216878364870323f   // 1/sqrt(192)
#define SC_IDXQ   0.08838834764831845f   // 1/sqrt(128)
#define SC_IDXW   0.17677669529663687f   // 1/sqrt(32)
#define NEGR      -1e30f
#define NEGL      -3.0e38f

typedef __bf16 bf16x8 __attribute__((ext_vector_type(8)));
typedef float  f32x4  __attribute__((ext_vector_type(4)));

// bf16 <-> f32 helpers (RNE)
__device__ __forceinline__ unsigned short f2b(float x) {
  union { float f; unsigned u; } v; v.f = x;
  unsigned r = v.u + 0x7FFFu + ((v.u >> 16) & 1u);
  return (unsigned short)(r >> 16);
}
__device__ __forceinline__ float b2f(unsigned short u) {
  union { unsigned u; float f; } v; v.u = ((unsigned)u) << 16;
  return v.f;
}

// ===================== helpers =====================
__device__ __forceinline__ float blk_sum256(float v, float* s) {
  #pragma unroll
  for (int o = 32; o > 0; o >>= 1) v += __shfl_down(v, o, 64);
  __syncthreads();
  if ((threadIdx.x & 63) == 0) s[threadIdx.x >> 6] = v;
  __syncthreads();
  return s[0] + s[1] + s[2] + s[3];
}

// ===================== prelude: res = hs+resid; hb = bf16(rms(res)*w) =====================
__global__ __launch_bounds__(256) void k_prelude(const float* __restrict__ hs,
                                                 const float* __restrict__ rsd,
                                                 const float* __restrict__ w,
                                                 float* __restrict__ res,
                                                 unsigned short* __restrict__ hb) {
  int t = blockIdx.x;
  __shared__ float scr[4];
  float vals[8]; float ss = 0.f;
  #pragma unroll
  for (int r = 0; r < 8; r++) {
    int d = threadIdx.x + 256*r;
    float v = hs[(size_t)t*HID + d] + rsd[(size_t)t*HID + d];
    vals[r] = v; res[(size_t)t*HID + d] = v; ss = fmaf(v, v, ss);
  }
  ss = blk_sum256(ss, scr);
  float inv = 1.f/sqrtf(ss/(float)HID + 1e-6f);
  #pragma unroll
  for (int r = 0; r < 8; r++) {
    int d = threadIdx.x + 256*r;
    hb[(size_t)t*HID + d] = f2b(vals[r]*inv*w[d]);
  }
}

// res2 = attn + res -> d_out; h2 f32 + h2 bf16
__global__ __launch_bounds__(256) void k_res2(const float* __restrict__ attn,
                                              const float* __restrict__ res,
                                              const float* __restrict__ w,
                                              float* __restrict__ res2_out,
                                              float* __restrict__ h2,
                                              unsigned short* __restrict__ h2b) {
  int t = blockIdx.x;
  __shared__ float scr[4];
  float vals[8]; float ss = 0.f;
  #pragma unroll
  for (int r = 0; r < 8; r++) {
    int d = threadIdx.x + 256*r;
    float v = attn[(size_t)t*HID + d] + res[(size_t)t*HID + d];
    vals[r] = v; res2_out[(size_t)t*HID + d] = v; ss = fmaf(v, v, ss);
  }
  ss = blk_sum256(ss, scr);
  float inv = 1.f/sqrtf(ss/(float)HID + 1e-6f);
  #pragma unroll
  for (int r = 0; r < 8; r++) {
    int d = threadIdx.x + 256*r;
    float o = vals[r]*inv*w[d];
    h2[(size_t)t*HID + d] = o;
    h2b[(size_t)t*HID + d] = f2b(o);
  }
}

// ===================== rope cos/sin tables (fp64 internally) =====================
__global__ void k_ropecs(const int* __restrict__ pos, float* __restrict__ cosb, float* __restrict__ sinb) {
  int i = blockIdx.x*256 + threadIdx.x;
  if (i >= TT*32) return;
  int t = i >> 5, k = i & 31;
  double inv = pow(10000.0, -((double)(2*k))/64.0);
  double f = (double)pos[t] * inv;
  cosb[i] = (float)cos(f);
  sinb[i] = (float)sin(f);
}

// ===================== f32 -> bf16 convert (with zero tail pad) =====================
__global__ void k_f2b(const float* __restrict__ s, unsigned short* __restrict__ d,
                      long long n, long long ntot) {
  long long stride = (long long)gridDim.x * 1024;
  for (long long i = ((long long)blockIdx.x*256 + threadIdx.x)*4; i < ntot; i += stride) {
    float x0, x1, x2, x3;
    if (i + 3 < n) { float4 v = *(const float4*)(s + i); x0=v.x; x1=v.y; x2=v.z; x3=v.w; }
    else {
      x0 = (i   < n) ? s[i]   : 0.f; x1 = (i+1 < n) ? s[i+1] : 0.f;
      x2 = (i+2 < n) ? s[i+2] : 0.f; x3 = (i+3 < n) ? s[i+3] : 0.f;
    }
    ushort4 o; o.x=f2b(x0); o.y=f2b(x1); o.z=f2b(x2); o.w=f2b(x3);
    *(ushort4*)(d + i) = o;
  }
}

// ===================== transpose + convert: src (R,C) f32 -> dst (C,R) bf16, batched z =====================
__global__ __launch_bounds__(256) void k_tconvb(const float* __restrict__ src,
                                                unsigned short* __restrict__ dst,
                                                int R, int C) {
  src += (size_t)blockIdx.z * R * C;
  dst += (size_t)blockIdx.z * R * C;
  __shared__ float tile[32][33];
  int c0 = blockIdx.x * 32, r0 = blockIdx.y * 32;
  int tx = threadIdx.x & 31, ty = threadIdx.x >> 5;
  #pragma unroll
  for (int i = 0; i < 4; i++) {
    int r = r0 + ty + i*8;
    tile[ty + i*8][tx] = src[(size_t)r*C + c0 + tx];
  }
  __syncthreads();
  #pragma unroll
  for (int i = 0; i < 4; i++) {
    int c = c0 + ty + i*8;
    dst[(size_t)c*R + r0 + tx] = f2b(tile[tx][ty + i*8]);
  }
}

// ===================== MFMA bf16 GEMM: C(M,N) = alpha * A(M,K) @ B(N,K)^T =====================
// A,B bf16 (ushort). 128x128 tile, 4 waves (2x2), BK=64, XOR-swizzled LDS.
// cskip >= 0: causal block skip — drop the block if col0 > row0 + cskip.
// nseg>1: accumulate over segments (A += segA, B += segB per segment) — used for MoE down.
template<bool STORE_BF16>
__global__ __launch_bounds__(256) void k_mgemm(const unsigned short* __restrict__ A, int lda, long long sA,
                                               const unsigned short* __restrict__ B, int ldb, long long sB,
                                               void* __restrict__ Cv, int ldc, long long sC,
                                               int N, int K, float alpha, int cskip,
                                               int nseg, long long segA, long long segB) {
  const int row0 = blockIdx.y * 128;
  const int col0 = blockIdx.x * 128;
  if (cskip >= 0 && col0 > row0 + cskip) return;
  __shared__ __align__(16) unsigned short As[128*64];
  __shared__ __align__(16) unsigned short Bs[128*64];
  const int tid  = threadIdx.x;
  const int wave = tid >> 6, lane = tid & 63;
  const int wm = wave >> 1, wn = wave & 1;
  A += (size_t)blockIdx.z * (size_t)sA;
  B += (size_t)blockIdx.z * (size_t)sB;

  f32x4 acc[4][4] = {};

  const int l15 = lane & 15, l4 = lane >> 4;
  const int sx = l15 & 7;

  for (int seg = 0; seg < nseg; seg++) {
    const unsigned short* Ab = A + (size_t)seg * segA;
    const unsigned short* Bb = B + (size_t)seg * segB;
    for (int k0 = 0; k0 < K; k0 += 64) {
      __syncthreads();
      #pragma unroll
      for (int it = 0; it < 4; it++) {
        int sidx = tid + 256*it;          // 0..1023 (128 rows x 8 slots)
        int r = sidx >> 3, s = sidx & 7;
        int ldsoff = r*64 + ((s ^ (r & 7)) << 3);
        uint4 va = *(const uint4*)(Ab + (size_t)(row0 + r)*lda + k0 + s*8);
        *(uint4*)&As[ldsoff] = va;
        uint4 vb = *(const uint4*)(Bb + (size_t)(col0 + r)*ldb + k0 + s*8);
        *(uint4*)&Bs[ldsoff] = vb;
      }
      __syncthreads();
      #pragma unroll
      for (int kc = 0; kc < 2; kc++) {
        const int sl = ((kc*4 + l4) ^ sx) << 3;
        bf16x8 fa[4], fb[4];
        #pragma unroll
        for (int mf = 0; mf < 4; mf++)
          fa[mf] = *(const bf16x8*)&As[(wm*64 + mf*16 + l15)*64 + sl];
        #pragma unroll
        for (int nf = 0; nf < 4; nf++)
          fb[nf] = *(const bf16x8*)&Bs[(wn*64 + nf*16 + l15)*64 + sl];
        #pragma unroll
        for (int mf = 0; mf < 4; mf++)
          #pragma unroll
          for (int nf = 0; nf < 4; nf++)
            acc[mf][nf] = __builtin_amdgcn_mfma_f32_16x16x32_bf16(fa[mf], fb[nf], acc[mf][nf], 0, 0, 0);
      }
    }
  }

  // C write: col = lane&15, row = (lane>>4)*4 + reg  [m89-verified]
  #pragma unroll
  for (int mf = 0; mf < 4; mf++) {
    #pragma unroll
    for (int nf = 0; nf < 4; nf++) {
      int n = col0 + wn*64 + nf*16 + l15;
      if (n < N) {
        #pragma unroll
        for (int r = 0; r < 4; r++) {
          int m = row0 + wm*64 + mf*16 + l4*4 + r;
          size_t idx = (size_t)m*ldc + n;
          float v = acc[mf][nf][r] * alpha;
          if (STORE_BF16) ((unsigned short*)Cv)[(size_t)blockIdx.z*sC + idx] = f2b(v);
          else            ((float*)Cv)[(size_t)blockIdx.z*sC + idx] = v;
        }
      }
    }
  }
}

// ===================== post-s1 =====================
__global__ __launch_bounds__(256) void k_post1(const float* __restrict__ s1,
    const float* __restrict__ wq, const float* __restrict__ wkv,
    const float* __restrict__ lnw, const float* __restrict__ lnb,
    const float* __restrict__ cosb, const float* __restrict__ sinb,
    unsigned short* __restrict__ qcb, float* __restrict__ kvc, float* __restrict__ kpe,
    float* __restrict__ idxk, float* __restrict__ idxw) {
  int t = blockIdx.x, tid = threadIdx.x;
  const float* row = s1 + (size_t)t*S1W;
  __shared__ float scr[4];
  __shared__ float yb[128];
  float ss = 0.f;
  for (int d = tid; d < QL; d += 256) { float v = row[d]; ss = fmaf(v,v,ss); }
  ss = blk_sum256(ss, scr);
  float inv = 1.f/sqrtf(ss/(float)QL + 1e-6f);
  for (int d = tid; d < QL; d += 256) qcb[(size_t)t*QL + d] = f2b(row[d]*inv*wq[d]);
  ss = 0.f;
  for (int d = tid; d < KVL; d += 256) { float v = row[QL+d]; ss = fmaf(v,v,ss); }
  ss = blk_sum256(ss, scr);
  inv = 1.f/sqrtf(ss/(float)KVL + 1e-6f);
  for (int d = tid; d < KVL; d += 256) kvc[(size_t)t*KVL + d] = row[QL+d]*inv*wkv[d];
  float sm = (tid < 128) ? row[1344 + tid] : 0.f;
  float tot = blk_sum256(sm, scr);
  float mean = tot / 128.f;
  float vs = 0.f;
  if (tid < 128) { float v = row[1344+tid] - mean; vs = v*v; }
  vs = blk_sum256(vs, scr);
  float ivn = 1.f/sqrtf(vs/128.f + 1e-6f);
  if (tid < 128) yb[tid] = (row[1344+tid]-mean)*ivn*lnw[tid] + lnb[tid];
  __syncthreads();
  if (tid < 32) {
    float c = cosb[t*32 + tid], s = sinb[t*32 + tid];
    idxk[(size_t)t*ID + tid]      = yb[tid]*c - yb[32+tid]*s;
    idxk[(size_t)t*ID + 32 + tid] = yb[32+tid]*c + yb[tid]*s;
    float x1 = row[1280+tid], x2 = row[1312+tid];
    kpe[(size_t)t*RD + tid]      = x1*c - x2*s;
    kpe[(size_t)t*RD + 32 + tid] = x2*c + x1*s;
    idxw[(size_t)t*IH + tid] = row[1472+tid] * SC_IDXW;
  } else if (tid >= 64 && tid < 128) {
    idxk[(size_t)t*ID + tid] = yb[tid];
  }
}

// ===================== post-s3 (in place f32) =====================
__global__ __launch_bounds__(256) void k_post3(float* __restrict__ s3,
                                               const float* __restrict__ cosb,
                                               const float* __restrict__ sinb) {
  int t = blockIdx.x, tid = threadIdx.x;
  float* row = s3 + (size_t)t*S3W;
  const float* cr = cosb + t*32; const float* sr = sinb + t*32;
  for (int p = tid; p < 1024; p += 256) {
    int h = p >> 5, d = p & 31;
    float c = cr[d], s = sr[d];
    float x1 = row[h*ID + d], x2 = row[h*ID + 32 + d];
    row[h*ID + d]      = (x1*c - x2*s) * SC_IDXQ;
    row[h*ID + 32 + d] = (x2*c + x1*s) * SC_IDXQ;
  }
  for (int p = tid; p < 2048; p += 256) {
    int h = p >> 6, d = 64 + (p & 63);
    row[h*ID + d] *= SC_IDXQ;
  }
  for (int p = tid; p < 512; p += 256) {
    int h = p >> 5, d = p & 31;
    float c = cr[d], s = sr[d];
    int base = IH*ID + h*192 + 128;
    float x1 = row[base + d], x2 = row[base + 32 + d];
    row[base + d]      = x1*c - x2*s;
    row[base + 32 + d] = x2*c + x1*s;
  }
}

// ===================== q_pe gather into QMQA concat layout (scaled) =====================
__global__ void k_qpe(const unsigned short* __restrict__ s3b, unsigned short* __restrict__ qm) {
  int i = blockIdx.x*256 + threadIdx.x;   // < 1024*16*64
  int t = i >> 10, r = i & 1023;
  int h = r >> 6, j = r & 63;
  float v = b2f(s3b[(size_t)t*S3W + IH*ID + h*192 + 128 + j]) * SCALE_ATT;
  qm[(size_t)t*9216 + h*576 + 512 + j] = f2b(v);
}

// ===================== kv concat bf16 =====================
__global__ void k_kvb(const float* __restrict__ kvc, const float* __restrict__ kpe,
                      unsigned short* __restrict__ kvb) {
  int i = blockIdx.x*256 + threadIdx.x;   // < 1024*576
  int s = i / 576, d = i - s*576;
  float v = (d < 512) ? kvc[(size_t)s*KVL + d] : kpe[(size_t)s*RD + (d - 512)];
  kvb[i] = f2b(v);
}

// ===================== indexer head-reduce: isc += relu(IL)*w; finalize causal =====================
__global__ __launch_bounds__(256) void k_ired(const float* __restrict__ il,
                                              const float* __restrict__ idxw,
                                              float* __restrict__ isc,
                                              int first, int last, int h0) {
  int tr = blockIdx.x;            // 0..511 -> t = 512+tr
  int t = 512 + tr;
  int s0 = threadIdx.x * 4;
  float4 acc;
  if (first) acc = make_float4(0.f, 0.f, 0.f, 0.f);
  else       acc = *(float4*)(isc + (size_t)tr*TT + s0);
  #pragma unroll
  for (int hh = 0; hh < 8; hh++) {
    float w = idxw[t*IH + h0 + hh];
    float4 v = *(const float4*)(il + (size_t)hh*524288 + (size_t)tr*1024 + s0);
    acc.x += fmaxf(v.x, 0.f) * w;
    acc.y += fmaxf(v.y, 0.f) * w;
    acc.z += fmaxf(v.z, 0.f) * w;
    acc.w += fmaxf(v.w, 0.f) * w;
  }
  if (last) {
    if (s0     > t) acc.x = NEGR;
    if (s0 + 1 > t) acc.y = NEGR;
    if (s0 + 2 > t) acc.z = NEGR;
    if (s0 + 3 > t) acc.w = NEGR;
  }
  *(float4*)(isc + (size_t)tr*TT + s0) = acc;
}

// ===================== exact per-row top-512 (bitonic, tie -> lower index) =====================
__global__ __launch_bounds__(512) void k_topk(const float* __restrict__ isc,
                                              unsigned char* __restrict__ mask) {
  int t = 512 + blockIdx.x;
  const float* row = isc + (size_t)blockIdx.x * TT;
  __shared__ unsigned long long keys[1024];
  int tid = threadIdx.x;
  for (int i = tid; i < 1024; i += 512) {
    float v = row[i];
    unsigned int b = __float_as_uint(v);
    unsigned int u = (b & 0x80000000u) ? ~b : (b | 0x80000000u);
    keys[i] = ((unsigned long long)u << 32) | (unsigned int)(1023 - i);
  }
  __syncthreads();
  for (int k = 2; k <= 1024; k <<= 1) {
    for (int j = k >> 1; j > 0; j >>= 1) {
      int i = ((tid & ~(j - 1)) << 1) | (tid & (j - 1));
      int l = i | j;
      unsigned long long a = keys[i], b = keys[l];
      bool up = ((i & k) == 0);
      if ((a < b) == up) { keys[i] = b; keys[l] = a; }
      __syncthreads();
    }
  }
  unsigned char* mrow = mask + (size_t)t * TT;
  for (int p = tid; p < 1024; p += 512) {
    int s = 1023 - (int)(keys[p] & 0xFFFFFFFFu);
    mrow[s] = (p < 512) ? (unsigned char)1 : (unsigned char)0;
  }
}

// ===================== masked softmax over P rows (in place, bf16) =====================
__global__ __launch_bounds__(256) void k_psoft(unsigned short* __restrict__ pb,
                                               const unsigned char* __restrict__ mask) {
  int b = blockIdx.x;
  int t = b & 1023, h = b >> 10;
  unsigned short* row = pb + ((size_t)h << 20) + ((size_t)t << 10);
  int tid = threadIdx.x;
  __shared__ float scr[4];
  int s0 = tid * 4;
  ushort4 raw = *(const ushort4*)(row + s0);
  float v0 = b2f(raw.x), v1 = b2f(raw.y), v2 = b2f(raw.z), v3 = b2f(raw.w);
  bool m0, m1, m2, m3;
  if (t < 512) {
    m0 = (s0 <= t); m1 = (s0+1 <= t); m2 = (s0+2 <= t); m3 = (s0+3 <= t);
  } else {
    uchar4 mk = *(const uchar4*)(mask + (size_t)t*TT + s0);
    m0 = (s0 <= t) && mk.x; m1 = (s0+1 <= t) && mk.y;
    m2 = (s0+2 <= t) && mk.z; m3 = (s0+3 <= t) && mk.w;
  }
  float mx = NEGL;
  if (m0) mx = v0;
  if (m1) mx = fmaxf(mx, v1);
  if (m2) mx = fmaxf(mx, v2);
  if (m3) mx = fmaxf(mx, v3);
  #pragma unroll
  for (int o = 32; o > 0; o >>= 1) mx = fmaxf(mx, __shfl_down(mx, o, 64));
  __syncthreads();
  if ((tid & 63) == 0) scr[tid >> 6] = mx;
  __syncthreads();
  mx = fmaxf(fmaxf(scr[0], scr[1]), fmaxf(scr[2], scr[3]));
  float p0 = m0 ? expf(v0 - mx) : 0.f;
  float p1 = m1 ? expf(v1 - mx) : 0.f;
  float p2 = m2 ? expf(v2 - mx) : 0.f;
  float p3 = m3 ? expf(v3 - mx) : 0.f;
  float sum = blk_sum256((p0+p1)+(p2+p3), scr);
  float inv = 1.f / sum;
  ushort4 o;
  o.x = f2b(p0*inv); o.y = f2b(p1*inv); o.z = f2b(p2*inv); o.w = f2b(p3*inv);
  *(ushort4*)(row + s0) = o;
}

// ===================== gating / routing (f32 exact) =====================
__global__ __launch_bounds__(256) void k_gate(const float* __restrict__ h2,
                                              const float* __restrict__ gw,
                                              const float* __restrict__ gb,
                                              float* __restrict__ comb) {
  int t = blockIdx.x, tid = threadIdx.x;
  int e = tid >> 5, lane = tid & 31;
  __shared__ float gl[8];
  float p = 0.f;
  for (int d = lane; d < HID; d += 32) p = fmaf(h2[(size_t)t*HID+d], gw[(size_t)e*HID+d], p);
  #pragma unroll
  for (int o = 16; o > 0; o >>= 1) p += __shfl_down(p, o, 32);
  if (lane == 0) gl[e] = p;
  __syncthreads();
  if (tid == 0) {
    float sg[8], sc[8];
    #pragma unroll
    for (int i = 0; i < 8; i++) { sg[i] = 1.f/(1.f+expf(-gl[i])); sc[i] = sg[i] + gb[i]; }
    float gs[4];
    #pragma unroll
    for (int g = 0; g < 4; g++) gs[g] = sc[2*g] + sc[2*g+1];
    int g0 = 0;
    for (int g = 1; g < 4; g++) if (gs[g] > gs[g0]) g0 = g;
    int g1 = -1;
    for (int g = 0; g < 4; g++) { if (g == g0) continue; if (g1 < 0 || gs[g] > gs[g1]) g1 = g; }
    float wsum = 1e-20f;
    #pragma unroll
    for (int i = 0; i < 8; i++) { int g = i >> 1; if (g == g0 || g == g1) wsum += sg[i]; }
    #pragma unroll
    for (int i = 0; i < 8; i++) { int g = i >> 1; comb[t*8+i] = (g == g0 || g == g1) ? sg[i]/wsum*2.5f : 0.f; }
  }
}

// ===================== swiglu variants =====================
__global__ void k_swiglu_sh(const float* __restrict__ gus, unsigned short* __restrict__ act) {
  int i = blockIdx.x*256 + threadIdx.x;   // < 1024*512
  int t = i >> 9, c = i & 511;
  float g = gus[(size_t)t*1024 + c], u = gus[(size_t)t*1024 + 512 + c];
  act[i] = f2b(g/(1.f + expf(-g)) * u);
}
__global__ void k_swiglu8(const float* __restrict__ gus8, const float* __restrict__ comb,
                          unsigned short* __restrict__ act8) {
  long long i = (long long)blockIdx.x*256 + threadIdx.x;  // < 8*1024*512
  int e = (int)(i >> 19);
  int rem = (int)(i & 524287);
  int t = rem >> 9, c = rem & 511;
  const float* g0 = gus8 + (size_t)e*1048576 + (size_t)t*1024;
  float g = g0[c], u = g0[512 + c];
  act8[i] = f2b(g/(1.f + expf(-g)) * u * comb[t*8 + e]);
}

__global__ void k_add(const float* __restrict__ a, const float* __restrict__ b, float* __restrict__ o) {
  int i = blockIdx.x*256 + threadIdx.x;
  o[i] = a[i] + b[i];
}

// ===================== launch =====================
extern "C" void kernel_launch(void* const* d_in, const int* in_sizes, int n_in,
                              void* d_out, int out_size, void* d_ws, size_t ws_size,
                              hipStream_t stream) {
  const int*   positions = (const int*)d_in[0];
  const float* hs     = (const float*)d_in[1];
  const float* rsd    = (const float*)d_in[2];
  const float* w_in   = (const float*)d_in[3];
  const float* w_post = (const float*)d_in[4];
  const float* w_s1   = (const float*)d_in[5];
  const float* w_qln  = (const float*)d_in[6];
  const float* w_kvln = (const float*)d_in[7];
  const float* iklnw  = (const float*)d_in[8];
  const float* iklnb  = (const float*)d_in[9];
  const float* w_s3   = (const float*)d_in[10];
  const float* wukt   = (const float*)d_in[11];
  const float* wuv    = (const float*)d_in[12];
  const float* w_o    = (const float*)d_in[13];
  const float* gate_w = (const float*)d_in[14];
  const float* gate_b = (const float*)d_in[15];
  const float* sh_gu  = (const float*)d_in[16];
  const float* sh_dn  = (const float*)d_in[17];
  const float* ex_gu  = (const float*)d_in[18];
  const float* ex_dn  = (const float*)d_in[19];

  float* ws = (float*)d_ws;
  typedef unsigned short ush;
  // -------- workspace layout (float units), phase-disjoint aliasing; peak 32,808,960 f = 131.2 MB --------
  float* RES   = ws + 0;          // 2,097,152
  float* COSB  = ws + 2097152;    // 32,768
  float* SINB  = ws + 2129920;    // 32,768
  float* KVC   = ws + 2162688;    // 524,288
  float* KPE   = ws + 2686976;    // 65,536
  float* IDXK  = ws + 2752512;    // 131,072
  float* IDXW  = ws + 2883584;    // 32,768
  float* COMB  = ws + 2916352;    // 8,192
  // phase A
  ush*   HB    = (ush*)(ws + 2924544);   // 2,097,152 ush
  ush*   WS1B  = (ush*)(ws + 3973120);   // 3,145,728 ush (1536x2048 padded)
  float* S1    = ws + 5545984;           // 1,540,096
  ush*   QCB   = (ush*)(ws + 7086080);   // 786,432 ush
  ush*   WS3B  = (ush*)(ws + 7479296);   // 5,505,024 ush
  ush*   WOB   = (ush*)(ws + 7479296);   // alias WS3B; converted AFTER s3 GEMM
  float* S3    = ws + 10231808;          // 7,340,032
  ush*   S3B   = (ush*)(ws + 17571840);  // 7,340,032 ush
  ush*   WUKTB = (ush*)(ws + 21241856);  // 1,048,576 ush
  ush*   QMQAB = (ush*)(ws + 21766144);  // 9,437,184 ush : [t][h][576], ends 26,484,736
  float* ISC   = ws + 26484736;          // 524,288
  unsigned char* MASK = (unsigned char*)(ws + 27009024); // 1,048,576 B
  ush*   WUVB  = (ush*)(ws + 27271168);  // 1,048,576 ush
  ush*   KVB   = (ush*)(ws + 27795456);  // 589,824 ush (region shared with ILB, time-disjoint)
  ush*   VTB   = (ush*)(ws + 28090368);  // 524,288 ush : V^T (512,1024)
  ush*   O2B   = (ush*)(ws + 28352512);  // 2,097,152 ush
  float* ILB   = ws + 27795456;          // 4,194,304 f : 8-head IL chunk [h][512][1024]; dead before KVB/VTB/O2B writes
  ush*   IDXKB = (ush*)(ws + 31989760);  // 131,072 ush : idx_k bf16 (dead before phase-B SHARED)
  ush*   PB    = (ush*)(ws + 10231808);  // 16,777,216 ush : [h][t][1024]; overlays dead S3 f32 + S3B head
  ush*   OHB   = (ush*)(ws + 18620416);  // 8,388,608 ush : [h][t][512]; overlays dead S3B tail/WUKTB/QMQAB head
  float* ATTN  = ws + 10231808;          // overlays dead PB
  // phase B (all written after k_res2)
  float* H2     = ws + 2924544;          // 2,097,152 (alias HB)
  ush*   H2B    = (ush*)(ws + 5021696);  // 2,097,152 ush
  ush*   SHGUB  = (ush*)(ws + 6070272);  // 2,097,152 ush
  ush*   SHDNB  = (ush*)(ws + 7118848);  // 1,048,576 ush
  ush*   EXGUB  = (ush*)(ws + 7643136);  // 16,777,216 ush
  ush*   EXDNB  = (ush*)(ws + 16031744); // 8,388,608 ush
  float* GUS8   = ws + 20226048;         // 8,388,608
  float* GUSsh  = ws + 20226048;         // alias (consumed before MoE gu)
  ush*   SHACTB = (ush*)(ws + 21274624); // 524,288 ush (inside GUS8, time-disjoint)
  ush*   ACTB8  = (ush*)(ws + 28614656); // 4,194,304 ush
  float* SHARED = ws + 30711808;         // 2,097,152
  float* ROUTED = ws + 0;                // alias RES (dead after res2)

  float* OUT0 = (float*)d_out;
  float* OUT_RES2 = OUT0 + (size_t)TT*HID;

  // 1. prelude
  k_prelude<<<TT, 256, 0, stream>>>(hs, rsd, w_in, RES, HB);
  k_ropecs<<<(TT*32)/256, 256, 0, stream>>>(positions, COSB, SINB);
  // 2. early weight conversions
  k_f2b<<<1024, 256, 0, stream>>>(w_s1, WS1B, 3080192LL, 3145728LL);  // pad rows 1504..1535 = 0
  k_f2b<<<1024, 256, 0, stream>>>(w_s3, WS3B, 5505024LL, 5505024LL);
  k_tconvb<<<dim3(16,4,16), 256, 0, stream>>>(wukt, WUKTB, 128, 512);
  k_tconvb<<<dim3(4,16,16), 256, 0, stream>>>(wuv, WUVB, 512, 128);
  // 3. s1 = h @ w_s1^T
  k_mgemm<false><<<dim3(12,8,1), 256, 0, stream>>>(HB, 2048, 0, WS1B, 2048, 0, S1, S1W, 0, 1504, 2048, 1.f, -1, 1, 0, 0);
  // 4. post-s1 + idx_k -> bf16
  k_post1<<<TT, 256, 0, stream>>>(S1, w_qln, w_kvln, iklnw, iklnb, COSB, SINB, QCB, KVC, KPE, IDXK, IDXW);
  k_f2b<<<128, 256, 0, stream>>>(IDXK, IDXKB, 131072LL, 131072LL);
  // 5. s3 = q_c @ w_s3^T
  k_mgemm<false><<<dim3(56,8,1), 256, 0, stream>>>(QCB, 768, 0, WS3B, 768, 0, S3, S3W, 0, S3W, 768, 1.f, -1, 1, 0, 0);
  // 6. post-s3 + convert s3 -> bf16 ; convert w_o (into WS3B slot, now dead)
  k_post3<<<TT, 256, 0, stream>>>(S3, COSB, SINB);
  k_f2b<<<1024, 256, 0, stream>>>(S3, (ush*)S3B, 7340032LL, 7340032LL);
  k_f2b<<<1024, 256, 0, stream>>>(w_o, WOB, 4194304LL, 4194304LL);
  // 7. ql_nope -> QMQAB[:, :, 0:512] with SCALE_ATT folded; q_pe -> cols 512:576
  k_mgemm<true><<<dim3(4,8,16), 256, 0, stream>>>(S3B + 4096, S3W, 192, WUKTB, 128, 65536, QMQAB, 9216, 576, 512, 128, SCALE_ATT, -1, 1, 0, 0);
  k_qpe<<<4096, 256, 0, stream>>>(S3B, QMQAB);
  // 8. indexer scores via MFMA: IL chunks of 8 heads (f32) + relu-weighted head reduce
  for (int c = 0; c < 4; c++) {
    k_mgemm<false><<<dim3(8,4,8), 256, 0, stream>>>(S3B + (size_t)512*S3W + c*1024, S3W, 128,
                                                    IDXKB, 128, 0,
                                                    ILB, 1024, 524288,
                                                    1024, 128, 1.f, 639, 1, 0, 0);
    k_ired<<<512, 256, 0, stream>>>(ILB, IDXW, ISC, c == 0, c == 3, c*8);
  }
  // 9. exact top-512
  k_topk<<<512, 512, 0, stream>>>(ISC, MASK);
  // 10. KV concat bf16 + V^T bf16
  k_kvb<<<2304, 256, 0, stream>>>(KVC, KPE, KVB);
  k_tconvb<<<dim3(16,32,1), 256, 0, stream>>>(KVC, VTB, 1024, 512);
  // 11. logits P = Qmqa @ KV^T (per head), pre-scaled, causal block-skip -> bf16
  k_mgemm<true><<<dim3(8,8,16), 256, 0, stream>>>(QMQAB, 9216, 576, KVB, 576, 0, PB, 1024, 1048576, 1024, 576, 1.f, 127, 1, 0, 0);
  // 12. masked softmax in place (writes zeros into all masked entries)
  k_psoft<<<16384, 256, 0, stream>>>(PB, MASK);
  // 13. O = P @ V (per head) -> OHB [h][t][512] bf16
  k_mgemm<true><<<dim3(4,8,16), 256, 0, stream>>>(PB, 1024, 1048576, VTB, 1024, 0, OHB, 512, 524288, 512, 1024, 1.f, -1, 1, 0, 0);
  // 14. o2 = O @ W_UV (per head) -> O2B [t][h*128]
  k_mgemm<true><<<dim3(1,8,16), 256, 0, stream>>>(OHB, 512, 524288, WUVB, 512, 65536, O2B, 2048, 128, 128, 512, 1.f, -1, 1, 0, 0);
  // 15. attn_out = o2 @ w_o^T
  k_mgemm<false><<<dim3(16,8,1), 256, 0, stream>>>(O2B, 2048, 0, WOB, 2048, 0, ATTN, 2048, 0, 2048, 2048, 1.f, -1, 1, 0, 0);
  // 16. res2 + h2
  k_res2<<<TT, 256, 0, stream>>>(ATTN, RES, w_post, OUT_RES2, H2, H2B);
  // 17. routing (f32)
  k_gate<<<TT, 256, 0, stream>>>(H2, gate_w, gate_b, COMB);
  // 18. late weight conversions
  k_f2b<<<1024, 256, 0, stream>>>(sh_gu, SHGUB, 2097152LL, 2097152LL);
  k_f2b<<<1024, 256, 0, stream>>>(sh_dn, SHDNB, 1048576LL, 1048576LL);
  k_f2b<<<1024, 256, 0, stream>>>(ex_gu, EXGUB, 16777216LL, 16777216LL);
  k_f2b<<<1024, 256, 0, stream>>>(ex_dn, EXDNB, 8388608LL, 8388608LL);
  // 19. shared expert
  k_mgemm<false><<<dim3(8,8,1), 256, 0, stream>>>(H2B, 2048, 0, SHGUB, 2048, 0, GUSsh, 1024, 0, 1024, 2048, 1.f, -1, 1, 0, 0);
  k_swiglu_sh<<<2048, 256, 0, stream>>>(GUSsh, SHACTB);
  k_mgemm<false><<<dim3(16,8,1), 256, 0, stream>>>(SHACTB, 512, 0, SHDNB, 512, 0, SHARED, 2048, 0, 2048, 512, 1.f, -1, 1, 0, 0);
  // 20. MoE: gate-up batched over experts; swiglu with comb folded; down folded over 8 expert segments
  k_mgemm<false><<<dim3(8,8,8), 256, 0, stream>>>(H2B, 2048, 0, EXGUB, 2048, 2097152, GUS8, 1024, 1048576, 1024, 2048, 1.f, -1, 1, 0, 0);
  k_swiglu8<<<16384, 256, 0, stream>>>(GUS8, COMB, ACTB8);
  k_mgemm<false><<<dim3(16,8,1), 256, 0, stream>>>(ACTB8, 512, 0, EXDNB, 512, 0, ROUTED, 2048, 0, 2048, 512, 1.f, -1, 8, 524288, 1048576);
  // 21. out = shared + routed
  k_add<<<(TT*HID)/256, 256, 0, stream>>>(SHARED, ROUTED, OUT0);
}

// Round 5
// 457.514 us; speedup vs baseline: 10.6168x; 1.2181x over previous
//
#include <hip/hip_runtime.h>
#include <math.h>

// ===================== constants =====================
static constexpr int TT  = 1024;
static constexpr int HID = 2048;
static constexpr int NH  = 16;
static constexpr int QL  = 768;
static constexpr int KVL = 512;
static constexpr int RD  = 64;     // rope dim
static constexpr int IH  = 32;     // idx heads
static constexpr int ID  = 128;    // idx dim
static constexpr int S1W = QL + KVL + RD + ID + IH;   // 1504
static constexpr int S3W = IH*ID + NH*(128+RD);       // 7168

#define SCALE_ATT 0.07216878364870323f   // 1/sqrt(192)
#define SC_IDXQ   0.08838834764831845f   // 1/sqrt(128)
#define SC_IDXW   0.17677669529663687f   // 1/sqrt(32)
#define NEGR      -1e30f
#define NEGL      -3.0e38f

typedef __bf16 bf16x8 __attribute__((ext_vector_type(8)));
typedef float  f32x4  __attribute__((ext_vector_type(4)));

// bf16 <-> f32 helpers (RNE)
__device__ __forceinline__ unsigned short f2b(float x) {
  union { float f; unsigned u; } v; v.f = x;
  unsigned r = v.u + 0x7FFFu + ((v.u >> 16) & 1u);
  return (unsigned short)(r >> 16);
}
__device__ __forceinline__ float b2f(unsigned short u) {
  union { unsigned u; float f; } v; v.u = ((unsigned)u) << 16;
  return v.f;
}

// ===================== helpers =====================
__device__ __forceinline__ float blk_sum256(float v, float* s) {
  #pragma unroll
  for (int o = 32; o > 0; o >>= 1) v += __shfl_down(v, o, 64);
  __syncthreads();
  if ((threadIdx.x & 63) == 0) s[threadIdx.x >> 6] = v;
  __syncthreads();
  return s[0] + s[1] + s[2] + s[3];
}

// ===================== prelude: res = hs+resid; hb = bf16(rms(res)*w) =====================
__global__ __launch_bounds__(256) void k_prelude(const float* __restrict__ hs,
                                                 const float* __restrict__ rsd,
                                                 const float* __restrict__ w,
                                                 float* __restrict__ res,
                                                 unsigned short* __restrict__ hb) {
  int t = blockIdx.x;
  __shared__ float scr[4];
  float vals[8]; float ss = 0.f;
  #pragma unroll
  for (int r = 0; r < 8; r++) {
    int d = threadIdx.x + 256*r;
    float v = hs[(size_t)t*HID + d] + rsd[(size_t)t*HID + d];
    vals[r] = v; res[(size_t)t*HID + d] = v; ss = fmaf(v, v, ss);
  }
  ss = blk_sum256(ss, scr);
  float inv = 1.f/sqrtf(ss/(float)HID + 1e-6f);
  #pragma unroll
  for (int r = 0; r < 8; r++) {
    int d = threadIdx.x + 256*r;
    hb[(size_t)t*HID + d] = f2b(vals[r]*inv*w[d]);
  }
}

// res2 = attn1+attn2 + res -> d_out; h2 f32 + h2 bf16
__global__ __launch_bounds__(256) void k_res2(const float* __restrict__ attn1,
                                              const float* __restrict__ attn2,
                                              const float* __restrict__ res,
                                              const float* __restrict__ w,
                                              float* __restrict__ res2_out,
                                              float* __restrict__ h2,
                                              unsigned short* __restrict__ h2b) {
  int t = blockIdx.x;
  __shared__ float scr[4];
  float vals[8]; float ss = 0.f;
  #pragma unroll
  for (int r = 0; r < 8; r++) {
    int d = threadIdx.x + 256*r;
    float v = attn1[(size_t)t*HID + d] + attn2[(size_t)t*HID + d] + res[(size_t)t*HID + d];
    vals[r] = v; res2_out[(size_t)t*HID + d] = v; ss = fmaf(v, v, ss);
  }
  ss = blk_sum256(ss, scr);
  float inv = 1.f/sqrtf(ss/(float)HID + 1e-6f);
  #pragma unroll
  for (int r = 0; r < 8; r++) {
    int d = threadIdx.x + 256*r;
    float o = vals[r]*inv*w[d];
    h2[(size_t)t*HID + d] = o;
    h2b[(size_t)t*HID + d] = f2b(o);
  }
}

// ===================== rope cos/sin tables (fp64 internally) =====================
__global__ void k_ropecs(const int* __restrict__ pos, float* __restrict__ cosb, float* __restrict__ sinb) {
  int i = blockIdx.x*256 + threadIdx.x;
  if (i >= TT*32) return;
  int t = i >> 5, k = i & 31;
  double inv = pow(10000.0, -((double)(2*k))/64.0);
  double f = (double)pos[t] * inv;
  cosb[i] = (float)cos(f);
  sinb[i] = (float)sin(f);
}

// ===================== f32 -> bf16 convert (with zero tail pad) =====================
__global__ void k_f2b(const float* __restrict__ s, unsigned short* __restrict__ d,
                      long long n, long long ntot) {
  long long stride = (long long)gridDim.x * 1024;
  for (long long i = ((long long)blockIdx.x*256 + threadIdx.x)*4; i < ntot; i += stride) {
    float x0, x1, x2, x3;
    if (i + 3 < n) { float4 v = *(const float4*)(s + i); x0=v.x; x1=v.y; x2=v.z; x3=v.w; }
    else {
      x0 = (i   < n) ? s[i]   : 0.f; x1 = (i+1 < n) ? s[i+1] : 0.f;
      x2 = (i+2 < n) ? s[i+2] : 0.f; x3 = (i+3 < n) ? s[i+3] : 0.f;
    }
    ushort4 o; o.x=f2b(x0); o.y=f2b(x1); o.z=f2b(x2); o.w=f2b(x3);
    *(ushort4*)(d + i) = o;
  }
}

// 4-segment fused convert (all n multiples of 4)
__global__ void k_f2b4(const float* __restrict__ s0, unsigned short* __restrict__ d0, long long n0,
                       const float* __restrict__ s1, unsigned short* __restrict__ d1, long long n1,
                       const float* __restrict__ s2, unsigned short* __restrict__ d2, long long n2,
                       const float* __restrict__ s3, unsigned short* __restrict__ d3, long long n3) {
  long long ntot = n0 + n1 + n2 + n3;
  long long stride = (long long)gridDim.x * 1024;
  for (long long i = ((long long)blockIdx.x*256 + threadIdx.x)*4; i < ntot; i += stride) {
    const float* s; unsigned short* d; long long j = i;
    if (j < n0) { s = s0; d = d0; }
    else { j -= n0;
      if (j < n1) { s = s1; d = d1; }
      else { j -= n1;
        if (j < n2) { s = s2; d = d2; }
        else { j -= n2; s = s3; d = d3; } } }
    float4 v = *(const float4*)(s + j);
    ushort4 o; o.x=f2b(v.x); o.y=f2b(v.y); o.z=f2b(v.z); o.w=f2b(v.w);
    *(ushort4*)(d + j) = o;
  }
}

// ===================== transpose + convert: src (R,C) f32 -> dst (C,R) bf16, batched z =====================
__global__ __launch_bounds__(256) void k_tconvb(const float* __restrict__ src,
                                                unsigned short* __restrict__ dst,
                                                int R, int C) {
  src += (size_t)blockIdx.z * R * C;
  dst += (size_t)blockIdx.z * R * C;
  __shared__ float tile[32][33];
  int c0 = blockIdx.x * 32, r0 = blockIdx.y * 32;
  int tx = threadIdx.x & 31, ty = threadIdx.x >> 5;
  #pragma unroll
  for (int i = 0; i < 4; i++) {
    int r = r0 + ty + i*8;
    tile[ty + i*8][tx] = src[(size_t)r*C + c0 + tx];
  }
  __syncthreads();
  #pragma unroll
  for (int i = 0; i < 4; i++) {
    int c = c0 + ty + i*8;
    dst[(size_t)c*R + r0 + tx] = f2b(tile[tx][ty + i*8]);
  }
}

// ===================== MFMA bf16 GEMM: C(M,N) = alpha * A(M,K) @ B(N,K)^T =====================
// A,B bf16 (ushort). 128x128 tile, 4 waves (2x2), BK=64, XOR-swizzled LDS.
// cskip >= 0: causal block skip — drop the block if col0 > row0 + cskip.
// nseg>1: accumulate over segments (A += segA, B += segB per segment).
// blockIdx.z advances A/B/C by sA/sB/sC (element units) — used for batching AND split-K.
template<bool STORE_BF16>
__global__ __launch_bounds__(256) void k_mgemm(const unsigned short* __restrict__ A, int lda, long long sA,
                                               const unsigned short* __restrict__ B, int ldb, long long sB,
                                               void* __restrict__ Cv, int ldc, long long sC,
                                               int N, int K, float alpha, int cskip,
                                               int nseg, long long segA, long long segB) {
  const int row0 = blockIdx.y * 128;
  const int col0 = blockIdx.x * 128;
  if (cskip >= 0 && col0 > row0 + cskip) return;
  __shared__ __align__(16) unsigned short As[128*64];
  __shared__ __align__(16) unsigned short Bs[128*64];
  const int tid  = threadIdx.x;
  const int wave = tid >> 6, lane = tid & 63;
  const int wm = wave >> 1, wn = wave & 1;
  A += (size_t)blockIdx.z * (size_t)sA;
  B += (size_t)blockIdx.z * (size_t)sB;

  f32x4 acc[4][4] = {};

  const int l15 = lane & 15, l4 = lane >> 4;
  const int sx = l15 & 7;

  for (int seg = 0; seg < nseg; seg++) {
    const unsigned short* Ab = A + (size_t)seg * segA;
    const unsigned short* Bb = B + (size_t)seg * segB;
    for (int k0 = 0; k0 < K; k0 += 64) {
      __syncthreads();
      #pragma unroll
      for (int it = 0; it < 4; it++) {
        int sidx = tid + 256*it;          // 0..1023 (128 rows x 8 slots)
        int r = sidx >> 3, s = sidx & 7;
        int ldsoff = r*64 + ((s ^ (r & 7)) << 3);
        uint4 va = *(const uint4*)(Ab + (size_t)(row0 + r)*lda + k0 + s*8);
        *(uint4*)&As[ldsoff] = va;
        uint4 vb = *(const uint4*)(Bb + (size_t)(col0 + r)*ldb + k0 + s*8);
        *(uint4*)&Bs[ldsoff] = vb;
      }
      __syncthreads();
      #pragma unroll
      for (int kc = 0; kc < 2; kc++) {
        const int sl = ((kc*4 + l4) ^ sx) << 3;
        bf16x8 fa[4], fb[4];
        #pragma unroll
        for (int mf = 0; mf < 4; mf++)
          fa[mf] = *(const bf16x8*)&As[(wm*64 + mf*16 + l15)*64 + sl];
        #pragma unroll
        for (int nf = 0; nf < 4; nf++)
          fb[nf] = *(const bf16x8*)&Bs[(wn*64 + nf*16 + l15)*64 + sl];
        #pragma unroll
        for (int mf = 0; mf < 4; mf++)
          #pragma unroll
          for (int nf = 0; nf < 4; nf++)
            acc[mf][nf] = __builtin_amdgcn_mfma_f32_16x16x32_bf16(fa[mf], fb[nf], acc[mf][nf], 0, 0, 0);
      }
    }
  }

  // C write: col = lane&15, row = (lane>>4)*4 + reg  [m89-verified]
  #pragma unroll
  for (int mf = 0; mf < 4; mf++) {
    #pragma unroll
    for (int nf = 0; nf < 4; nf++) {
      int n = col0 + wn*64 + nf*16 + l15;
      if (n < N) {
        #pragma unroll
        for (int r = 0; r < 4; r++) {
          int m = row0 + wm*64 + mf*16 + l4*4 + r;
          size_t idx = (size_t)m*ldc + n;
          float v = acc[mf][nf][r] * alpha;
          if (STORE_BF16) ((unsigned short*)Cv)[(size_t)blockIdx.z*sC + idx] = f2b(v);
          else            ((float*)Cv)[(size_t)blockIdx.z*sC + idx] = v;
        }
      }
    }
  }
}

// ===================== post-s1 (sums 2 split-K partials via LDS row) =====================
__global__ __launch_bounds__(256) void k_post1(const float* __restrict__ s1a,
    const float* __restrict__ s1b,
    const float* __restrict__ wq, const float* __restrict__ wkv,
    const float* __restrict__ lnw, const float* __restrict__ lnb,
    const float* __restrict__ cosb, const float* __restrict__ sinb,
    unsigned short* __restrict__ qcb, float* __restrict__ kvc, float* __restrict__ kpe,
    float* __restrict__ idxk, float* __restrict__ idxw) {
  int t = blockIdx.x, tid = threadIdx.x;
  __shared__ float rowb[S1W];
  __shared__ float scr[4];
  __shared__ float yb[128];
  for (int d = tid; d < S1W; d += 256)
    rowb[d] = s1a[(size_t)t*S1W + d] + s1b[(size_t)t*S1W + d];
  __syncthreads();
  float ss = 0.f;
  for (int d = tid; d < QL; d += 256) { float v = rowb[d]; ss = fmaf(v,v,ss); }
  ss = blk_sum256(ss, scr);
  float inv = 1.f/sqrtf(ss/(float)QL + 1e-6f);
  for (int d = tid; d < QL; d += 256) qcb[(size_t)t*QL + d] = f2b(rowb[d]*inv*wq[d]);
  ss = 0.f;
  for (int d = tid; d < KVL; d += 256) { float v = rowb[QL+d]; ss = fmaf(v,v,ss); }
  ss = blk_sum256(ss, scr);
  inv = 1.f/sqrtf(ss/(float)KVL + 1e-6f);
  for (int d = tid; d < KVL; d += 256) kvc[(size_t)t*KVL + d] = rowb[QL+d]*inv*wkv[d];
  float sm = (tid < 128) ? rowb[1344 + tid] : 0.f;
  float tot = blk_sum256(sm, scr);
  float mean = tot / 128.f;
  float vs = 0.f;
  if (tid < 128) { float v = rowb[1344+tid] - mean; vs = v*v; }
  vs = blk_sum256(vs, scr);
  float ivn = 1.f/sqrtf(vs/128.f + 1e-6f);
  if (tid < 128) yb[tid] = (rowb[1344+tid]-mean)*ivn*lnw[tid] + lnb[tid];
  __syncthreads();
  if (tid < 32) {
    float c = cosb[t*32 + tid], s = sinb[t*32 + tid];
    idxk[(size_t)t*ID + tid]      = yb[tid]*c - yb[32+tid]*s;
    idxk[(size_t)t*ID + 32 + tid] = yb[32+tid]*c + yb[tid]*s;
    float x1 = rowb[1280+tid], x2 = rowb[1312+tid];
    kpe[(size_t)t*RD + tid]      = x1*c - x2*s;
    kpe[(size_t)t*RD + 32 + tid] = x2*c + x1*s;
    idxw[(size_t)t*IH + tid] = rowb[1472+tid] * SC_IDXW;
  } else if (tid >= 64 && tid < 128) {
    idxk[(size_t)t*ID + tid] = yb[tid];
  }
}

// ===================== post-s3: rope/scale in LDS, write bf16 directly =====================
__global__ __launch_bounds__(256) void k_post3b(const float* __restrict__ s3,
                                                const float* __restrict__ cosb,
                                                const float* __restrict__ sinb,
                                                unsigned short* __restrict__ s3b) {
  int t = blockIdx.x, tid = threadIdx.x;
  const float* row = s3 + (size_t)t*S3W;
  __shared__ float buf[S3W];
  __shared__ float cs[32], sn[32];
  if (tid < 32) { cs[tid] = cosb[t*32+tid]; sn[tid] = sinb[t*32+tid]; }
  for (int d = tid; d < S3W; d += 256) buf[d] = row[d];
  __syncthreads();
  // idx_q rope pairs (disjoint address sets across the three loops)
  for (int p = tid; p < 1024; p += 256) {
    int h = p >> 5, d = p & 31;
    float c = cs[d], s = sn[d];
    float x1 = buf[h*ID + d], x2 = buf[h*ID + 32 + d];
    buf[h*ID + d]      = (x1*c - x2*s) * SC_IDXQ;
    buf[h*ID + 32 + d] = (x2*c + x1*s) * SC_IDXQ;
  }
  for (int p = tid; p < 2048; p += 256) {
    int h = p >> 6, d = 64 + (p & 63);
    buf[h*ID + d] *= SC_IDXQ;
  }
  for (int p = tid; p < 512; p += 256) {
    int h = p >> 5, d = p & 31;
    float c = cs[d], s = sn[d];
    int base = IH*ID + h*192 + 128;
    float x1 = buf[base + d], x2 = buf[base + 32 + d];
    buf[base + d]      = x1*c - x2*s;
    buf[base + 32 + d] = x2*c + x1*s;
  }
  __syncthreads();
  unsigned short* orow = s3b + (size_t)t*S3W;
  for (int g = tid*4; g < S3W; g += 1024) {
    ushort4 o;
    o.x = f2b(buf[g]); o.y = f2b(buf[g+1]); o.z = f2b(buf[g+2]); o.w = f2b(buf[g+3]);
    *(ushort4*)(orow + g) = o;
  }
}

// ===================== q_pe gather into QMQA concat layout (scaled) =====================
__global__ void k_qpe(const unsigned short* __restrict__ s3b, unsigned short* __restrict__ qm) {
  int i = blockIdx.x*256 + threadIdx.x;   // < 1024*16*64
  int t = i >> 10, r = i & 1023;
  int h = r >> 6, j = r & 63;
  float v = b2f(s3b[(size_t)t*S3W + IH*ID + h*192 + 128 + j]) * SCALE_ATT;
  qm[(size_t)t*9216 + h*576 + 512 + j] = f2b(v);
}

// ===================== kv concat bf16 =====================
__global__ void k_kvb(const float* __restrict__ kvc, const float* __restrict__ kpe,
                      unsigned short* __restrict__ kvb) {
  int i = blockIdx.x*256 + threadIdx.x;   // < 1024*576
  int s = i / 576, d = i - s*576;
  float v = (d < 512) ? kvc[(size_t)s*KVL + d] : kpe[(size_t)s*RD + (d - 512)];
  kvb[i] = f2b(v);
}

// ===================== indexer head-reduce: isc += relu(IL)*w; finalize causal =====================
__global__ __launch_bounds__(256) void k_ired(const float* __restrict__ il,
                                              const float* __restrict__ idxw,
                                              float* __restrict__ isc,
                                              int first, int last, int h0) {
  int tr = blockIdx.x;            // 0..511 -> t = 512+tr
  int t = 512 + tr;
  int s0 = threadIdx.x * 4;
  float4 acc;
  if (first) acc = make_float4(0.f, 0.f, 0.f, 0.f);
  else       acc = *(float4*)(isc + (size_t)tr*TT + s0);
  #pragma unroll
  for (int hh = 0; hh < 8; hh++) {
    float w = idxw[t*IH + h0 + hh];
    float4 v = *(const float4*)(il + (size_t)hh*524288 + (size_t)tr*1024 + s0);
    acc.x += fmaxf(v.x, 0.f) * w;
    acc.y += fmaxf(v.y, 0.f) * w;
    acc.z += fmaxf(v.z, 0.f) * w;
    acc.w += fmaxf(v.w, 0.f) * w;
  }
  if (last) {
    if (s0     > t) acc.x = NEGR;
    if (s0 + 1 > t) acc.y = NEGR;
    if (s0 + 2 > t) acc.z = NEGR;
    if (s0 + 3 > t) acc.w = NEGR;
  }
  *(float4*)(isc + (size_t)tr*TT + s0) = acc;
}

// ===================== exact per-row top-512 (bitonic, tie -> lower index) =====================
__global__ __launch_bounds__(512) void k_topk(const float* __restrict__ isc,
                                              unsigned char* __restrict__ mask) {
  int t = 512 + blockIdx.x;
  const float* row = isc + (size_t)blockIdx.x * TT;
  __shared__ unsigned long long keys[1024];
  int tid = threadIdx.x;
  for (int i = tid; i < 1024; i += 512) {
    float v = row[i];
    unsigned int b = __float_as_uint(v);
    unsigned int u = (b & 0x80000000u) ? ~b : (b | 0x80000000u);
    keys[i] = ((unsigned long long)u << 32) | (unsigned int)(1023 - i);
  }
  __syncthreads();
  for (int k = 2; k <= 1024; k <<= 1) {
    for (int j = k >> 1; j > 0; j >>= 1) {
      int i = ((tid & ~(j - 1)) << 1) | (tid & (j - 1));
      int l = i | j;
      unsigned long long a = keys[i], b = keys[l];
      bool up = ((i & k) == 0);
      if ((a < b) == up) { keys[i] = b; keys[l] = a; }
      __syncthreads();
    }
  }
  unsigned char* mrow = mask + (size_t)t * TT;
  for (int p = tid; p < 1024; p += 512) {
    int s = 1023 - (int)(keys[p] & 0xFFFFFFFFu);
    mrow[s] = (p < 512) ? (unsigned char)1 : (unsigned char)0;
  }
}

// ===================== masked softmax over P rows (in place, bf16) =====================
__global__ __launch_bounds__(256) void k_psoft(unsigned short* __restrict__ pb,
                                               const unsigned char* __restrict__ mask) {
  int b = blockIdx.x;
  int t = b & 1023, h = b >> 10;
  unsigned short* row = pb + ((size_t)h << 20) + ((size_t)t << 10);
  int tid = threadIdx.x;
  __shared__ float scr[4];
  int s0 = tid * 4;
  ushort4 raw = *(const ushort4*)(row + s0);
  float v0 = b2f(raw.x), v1 = b2f(raw.y), v2 = b2f(raw.z), v3 = b2f(raw.w);
  bool m0, m1, m2, m3;
  if (t < 512) {
    m0 = (s0 <= t); m1 = (s0+1 <= t); m2 = (s0+2 <= t); m3 = (s0+3 <= t);
  } else {
    uchar4 mk = *(const uchar4*)(mask + (size_t)t*TT + s0);
    m0 = (s0 <= t) && mk.x; m1 = (s0+1 <= t) && mk.y;
    m2 = (s0+2 <= t) && mk.z; m3 = (s0+3 <= t) && mk.w;
  }
  float mx = NEGL;
  if (m0) mx = v0;
  if (m1) mx = fmaxf(mx, v1);
  if (m2) mx = fmaxf(mx, v2);
  if (m3) mx = fmaxf(mx, v3);
  #pragma unroll
  for (int o = 32; o > 0; o >>= 1) mx = fmaxf(mx, __shfl_down(mx, o, 64));
  __syncthreads();
  if ((tid & 63) == 0) scr[tid >> 6] = mx;
  __syncthreads();
  mx = fmaxf(fmaxf(scr[0], scr[1]), fmaxf(scr[2], scr[3]));
  float p0 = m0 ? expf(v0 - mx) : 0.f;
  float p1 = m1 ? expf(v1 - mx) : 0.f;
  float p2 = m2 ? expf(v2 - mx) : 0.f;
  float p3 = m3 ? expf(v3 - mx) : 0.f;
  float sum = blk_sum256((p0+p1)+(p2+p3), scr);
  float inv = 1.f / sum;
  ushort4 o;
  o.x = f2b(p0*inv); o.y = f2b(p1*inv); o.z = f2b(p2*inv); o.w = f2b(p3*inv);
  *(ushort4*)(row + s0) = o;
}

// ===================== gating / routing (f32 exact) =====================
__global__ __launch_bounds__(256) void k_gate(const float* __restrict__ h2,
                                              const float* __restrict__ gw,
                                              const float* __restrict__ gb,
                                              float* __restrict__ comb) {
  int t = blockIdx.x, tid = threadIdx.x;
  int e = tid >> 5, lane = tid & 31;
  __shared__ float gl[8];
  float p = 0.f;
  for (int d = lane; d < HID; d += 32) p = fmaf(h2[(size_t)t*HID+d], gw[(size_t)e*HID+d], p);
  #pragma unroll
  for (int o = 16; o > 0; o >>= 1) p += __shfl_down(p, o, 32);
  if (lane == 0) gl[e] = p;
  __syncthreads();
  if (tid == 0) {
    float sg[8], sc[8];
    #pragma unroll
    for (int i = 0; i < 8; i++) { sg[i] = 1.f/(1.f+expf(-gl[i])); sc[i] = sg[i] + gb[i]; }
    float gs[4];
    #pragma unroll
    for (int g = 0; g < 4; g++) gs[g] = sc[2*g] + sc[2*g+1];
    int g0 = 0;
    for (int g = 1; g < 4; g++) if (gs[g] > gs[g0]) g0 = g;
    int g1 = -1;
    for (int g = 0; g < 4; g++) { if (g == g0) continue; if (g1 < 0 || gs[g] > gs[g1]) g1 = g; }
    float wsum = 1e-20f;
    #pragma unroll
    for (int i = 0; i < 8; i++) { int g = i >> 1; if (g == g0 || g == g1) wsum += sg[i]; }
    #pragma unroll
    for (int i = 0; i < 8; i++) { int g = i >> 1; comb[t*8+i] = (g == g0 || g == g1) ? sg[i]/wsum*2.5f : 0.f; }
  }
}

// ===================== swiglu over 9 experts (e==8 = shared, weight 1) =====================
__global__ void k_swiglu9(const float* __restrict__ gus9, const float* __restrict__ comb,
                          unsigned short* __restrict__ act9) {
  long long i = (long long)blockIdx.x*256 + threadIdx.x;  // < 9*1024*512
  int e = (int)(i >> 19);
  int rem = (int)(i & 524287);
  int t = rem >> 9, c = rem & 511;
  const float* g0 = gus9 + (size_t)e*1048576 + (size_t)t*1024;
  float g = g0[c], u = g0[512 + c];
  float w = (e < 8) ? comb[t*8 + e] : 1.f;
  act9[i] = f2b(g/(1.f + expf(-g)) * u * w);
}

// ===================== down-proj partial reduce: out = r0+r1+r2 =====================
__global__ void k_dnred(const float* __restrict__ r, float* __restrict__ o) {
  int i = (blockIdx.x*256 + threadIdx.x)*4;
  float4 a = *(const float4*)(r + i);
  float4 b = *(const float4*)(r + 2097152 + i);
  float4 c = *(const float4*)(r + 4194304 + i);
  float4 v;
  v.x = a.x + b.x + c.x; v.y = a.y + b.y + c.y;
  v.z = a.z + b.z + c.z; v.w = a.w + b.w + c.w;
  *(float4*)(o + i) = v;
}

// ===================== launch =====================
extern "C" void kernel_launch(void* const* d_in, const int* in_sizes, int n_in,
                              void* d_out, int out_size, void* d_ws, size_t ws_size,
                              hipStream_t stream) {
  const int*   positions = (const int*)d_in[0];
  const float* hs     = (const float*)d_in[1];
  const float* rsd    = (const float*)d_in[2];
  const float* w_in   = (const float*)d_in[3];
  const float* w_post = (const float*)d_in[4];
  const float* w_s1   = (const float*)d_in[5];
  const float* w_qln  = (const float*)d_in[6];
  const float* w_kvln = (const float*)d_in[7];
  const float* iklnw  = (const float*)d_in[8];
  const float* iklnb  = (const float*)d_in[9];
  const float* w_s3   = (const float*)d_in[10];
  const float* wukt   = (const float*)d_in[11];
  const float* wuv    = (const float*)d_in[12];
  const float* w_o    = (const float*)d_in[13];
  const float* gate_w = (const float*)d_in[14];
  const float* gate_b = (const float*)d_in[15];
  const float* sh_gu  = (const float*)d_in[16];
  const float* sh_dn  = (const float*)d_in[17];
  const float* ex_gu  = (const float*)d_in[18];
  const float* ex_dn  = (const float*)d_in[19];

  float* ws = (float*)d_ws;
  typedef unsigned short ush;
  // -------- workspace layout (float units), phase-disjoint aliasing; peak 32,055,296 f = 128.2 MB --------
  // persistent
  float* RES   = ws + 0;          // 2,097,152
  float* COSB  = ws + 2097152;    // 32,768
  float* SINB  = ws + 2129920;    // 32,768
  float* KVC   = ws + 2162688;    // 524,288
  float* KPE   = ws + 2686976;    // 65,536
  float* IDXK  = ws + 2752512;    // 131,072
  float* IDXW  = ws + 2883584;    // 32,768
  float* COMB  = ws + 2916352;    // 8,192
  // phase A
  ush*   HB    = (ush*)(ws + 2924544);   // 2,097,152 ush
  ush*   WS1B  = (ush*)(ws + 3973120);   // 3,145,728 ush (1536x2048 padded)
  float* S1P0  = ws + 5545984;           // 1,540,096 (split-K partial 0)
  ush*   QCB   = (ush*)(ws + 7086080);   // 786,432 ush
  ush*   WS3B  = (ush*)(ws + 7479296);   // 5,505,024 ush
  ush*   WOB   = (ush*)(ws + 7479296);   // alias WS3B; converted AFTER s3 GEMM
  float* S3    = ws + 10231808;          // 7,340,032 f32
  float* S1P1  = ws + 10231808;          // 1,540,096 (split-K partial 1; dead before S3 write)
  ush*   S3B   = (ush*)(ws + 17571840);  // 7,340,032 ush
  ush*   WUKTB = (ush*)(ws + 21241856);  // 1,048,576 ush
  ush*   QMQAB = (ush*)(ws + 21766144);  // 9,437,184 ush : [t][h][576], ends 26,484,736
  float* ISC   = ws + 26484736;          // 524,288
  unsigned char* MASK = (unsigned char*)(ws + 27009024); // 1,048,576 B
  ush*   WUVB  = (ush*)(ws + 27271168);  // 1,048,576 ush
  ush*   KVB   = (ush*)(ws + 27795456);  // 589,824 ush
  ush*   VTB   = (ush*)(ws + 28090368);  // 524,288 ush : V^T (512,1024)
  ush*   O2B   = (ush*)(ws + 28352512);  // 2,097,152 ush
  float* ILB   = ws + 27795456;          // 4,194,304 f : 8-head IL chunk (time-disjoint with KVB/VTB/O2B)
  ush*   IDXKB = (ush*)(ws + 31989760);  // 131,072 ush
  ush*   PB    = (ush*)(ws + 10231808);  // 16,777,216 ush : [h][t][1024] (overlays dead S3/S3B head)
  ush*   OHB   = (ush*)(ws + 18620416);  // 8,388,608 ush : [h][t][512]
  float* ATTNP = ws + 10231808;          // 2 x 2,097,152 (split-K partials; overlays dead PB)
  // phase B (all written after k_res2)
  float* H2     = ws + 2924544;          // 2,097,152 (alias HB)
  ush*   H2B    = (ush*)(ws + 5021696);  // 2,097,152 ush
  ush*   EXGUB  = (ush*)(ws + 6070272);  // 16,777,216 ush  -> ends f 14,458,880
  ush*   SHGUB  = (ush*)(ws + 14458880); // 2,097,152 ush (contiguous after EXGUB => z=8)
  ush*   EXDNB  = (ush*)(ws + 15507456); // 8,388,608 ush   -> ends f 19,701,760
  ush*   SHDNB  = (ush*)(ws + 19701760); // 1,048,576 ush (contiguous => segment 8)
  float* GUS9   = ws + 20226048;         // 9,437,184 f -> ends 29,663,232
  ush*   ACTB9  = (ush*)(ws + 29663232); // 4,718,592 ush -> ends f 32,022,528
  float* RPART  = ws + 20226048;         // 3 x 2,097,152 f (overlays dead GUS9)

  float* OUT0 = (float*)d_out;
  float* OUT_RES2 = OUT0 + (size_t)TT*HID;

  // 1. prelude + rope tables
  k_prelude<<<TT, 256, 0, stream>>>(hs, rsd, w_in, RES, HB);
  k_ropecs<<<(TT*32)/256, 256, 0, stream>>>(positions, COSB, SINB);
  // 2. early weight conversions
  k_f2b<<<1024, 256, 0, stream>>>(w_s1, WS1B, 3080192LL, 3145728LL);  // pad rows 1504..1535 = 0
  k_f2b<<<1024, 256, 0, stream>>>(w_s3, WS3B, 5505024LL, 5505024LL);
  k_tconvb<<<dim3(16,4,16), 256, 0, stream>>>(wukt, WUKTB, 128, 512);
  k_tconvb<<<dim3(4,16,16), 256, 0, stream>>>(wuv, WUVB, 512, 128);
  // 3. s1 = h @ w_s1^T, split-K z=2 (K halves of 1024) -> partials
  k_mgemm<false><<<dim3(12,8,2), 256, 0, stream>>>(HB, 2048, 1024, WS1B, 2048, 1024,
                                                   S1P0, S1W, 4685824, 1504, 1024, 1.f, -1, 1, 0, 0);
  // 4. post-s1 (sums partials) + idx_k -> bf16
  k_post1<<<TT, 256, 0, stream>>>(S1P0, S1P1, w_qln, w_kvln, iklnw, iklnb, COSB, SINB, QCB, KVC, KPE, IDXK, IDXW);
  k_f2b<<<128, 256, 0, stream>>>(IDXK, IDXKB, 131072LL, 131072LL);
  // 5. s3 = q_c @ w_s3^T
  k_mgemm<false><<<dim3(56,8,1), 256, 0, stream>>>(QCB, 768, 0, WS3B, 768, 0, S3, S3W, 0, S3W, 768, 1.f, -1, 1, 0, 0);
  // 6. post-s3: rope/scale + bf16 write fused ; convert w_o (into WS3B slot, now dead)
  k_post3b<<<TT, 256, 0, stream>>>(S3, COSB, SINB, (ush*)S3B);
  k_f2b<<<1024, 256, 0, stream>>>(w_o, WOB, 4194304LL, 4194304LL);
  // 7. ql_nope -> QMQAB[:, :, 0:512] with SCALE_ATT folded; q_pe -> cols 512:576
  k_mgemm<true><<<dim3(4,8,16), 256, 0, stream>>>(S3B + 4096, S3W, 192, WUKTB, 128, 65536, QMQAB, 9216, 576, 512, 128, SCALE_ATT, -1, 1, 0, 0);
  k_qpe<<<4096, 256, 0, stream>>>(S3B, QMQAB);
  // 8. indexer scores via MFMA: IL chunks of 8 heads (f32) + relu-weighted head reduce
  for (int c = 0; c < 4; c++) {
    k_mgemm<false><<<dim3(8,4,8), 256, 0, stream>>>(S3B + (size_t)512*S3W + c*1024, S3W, 128,
                                                    IDXKB, 128, 0,
                                                    ILB, 1024, 524288,
                                                    1024, 128, 1.f, 639, 1, 0, 0);
    k_ired<<<512, 256, 0, stream>>>(ILB, IDXW, ISC, c == 0, c == 3, c*8);
  }
  // 9. exact top-512
  k_topk<<<512, 512, 0, stream>>>(ISC, MASK);
  // 10. KV concat bf16 + V^T bf16
  k_kvb<<<2304, 256, 0, stream>>>(KVC, KPE, KVB);
  k_tconvb<<<dim3(16,32,1), 256, 0, stream>>>(KVC, VTB, 1024, 512);
  // 11. logits P = Qmqa @ KV^T (per head), pre-scaled, causal block-skip -> bf16
  k_mgemm<true><<<dim3(8,8,16), 256, 0, stream>>>(QMQAB, 9216, 576, KVB, 576, 0, PB, 1024, 1048576, 1024, 576, 1.f, 127, 1, 0, 0);
  // 12. masked softmax in place (writes zeros into all masked entries)
  k_psoft<<<16384, 256, 0, stream>>>(PB, MASK);
  // 13. O = P @ V (per head) -> OHB [h][t][512] bf16
  k_mgemm<true><<<dim3(4,8,16), 256, 0, stream>>>(PB, 1024, 1048576, VTB, 1024, 0, OHB, 512, 524288, 512, 1024, 1.f, -1, 1, 0, 0);
  // 14. o2 = O @ W_UV (per head) -> O2B [t][h*128]
  k_mgemm<true><<<dim3(1,8,16), 256, 0, stream>>>(OHB, 512, 524288, WUVB, 512, 65536, O2B, 2048, 128, 128, 512, 1.f, -1, 1, 0, 0);
  // 15. attn_out = o2 @ w_o^T, split-K z=2 -> partials
  k_mgemm<false><<<dim3(16,8,2), 256, 0, stream>>>(O2B, 2048, 1024, WOB, 2048, 1024,
                                                   ATTNP, 2048, 2097152, 2048, 1024, 1.f, -1, 1, 0, 0);
  // 16. res2 (sums partials) + h2
  k_res2<<<TT, 256, 0, stream>>>(ATTNP, ATTNP + 2097152, RES, w_post, OUT_RES2, H2, H2B);
  // 17. routing (f32)
  k_gate<<<TT, 256, 0, stream>>>(H2, gate_w, gate_b, COMB);
  // 18. fused late weight conversions (ex_gu | sh_gu | ex_dn | sh_dn)
  k_f2b4<<<2048, 256, 0, stream>>>(ex_gu, EXGUB, 16777216LL,
                                   sh_gu, SHGUB, 2097152LL,
                                   ex_dn, EXDNB, 8388608LL,
                                   sh_dn, SHDNB, 1048576LL);
  // 19. gate-up for 9 experts (z=8 = shared) -> GUS9 f32
  k_mgemm<false><<<dim3(8,8,9), 256, 0, stream>>>(H2B, 2048, 0, EXGUB, 2048, 2097152, GUS9, 1024, 1048576, 1024, 2048, 1.f, -1, 1, 0, 0);
  // 20. swiglu over 9 experts (comb folded; shared weight 1)
  k_swiglu9<<<18432, 256, 0, stream>>>(GUS9, COMB, ACTB9);
  // 21. down-proj: sum over 9 (act_e @ dn_e^T), split z=3 x (3 segments) -> partials
  k_mgemm<false><<<dim3(16,8,3), 256, 0, stream>>>(ACTB9, 512, 1572864, EXDNB, 512, 3145728,
                                                   RPART, 2048, 2097152, 2048, 512, 1.f, -1, 3, 524288, 1048576);
  // 22. out = P0+P1+P2 (shared + routed, deterministic)
  k_dnred<<<2048, 256, 0, stream>>>(RPART, OUT0);
}